// Round 3
// baseline (703.635 us; speedup 1.0000x reference)
//
#include <hip/hip_runtime.h>

// Fused causal self-attention block: B=4, S=2048, D=1024, H=16, dk=64.
// cast/transpose -> QKV GEMM (global_load_lds, V written transposed) ->
// flash attention (QBLK=128, V^T staged, T14 prefetch) -> out GEMM+residual -> LN.

typedef __attribute__((ext_vector_type(8))) short short8;
typedef __attribute__((ext_vector_type(4))) float f32x4;

#define S_LEN 2048
#define NH 16
#define DK 64
#define DMODEL 1024

__device__ inline unsigned short f2bf(float f) {
    unsigned int u = __builtin_bit_cast(unsigned int, f);
    unsigned int r = (u + 0x7fffu + ((u >> 16) & 1u)) >> 16;  // RNE
    return (unsigned short)r;
}

__device__ inline void gload16(const unsigned short* g, unsigned short* lds) {
    __builtin_amdgcn_global_load_lds(
        (const __attribute__((address_space(1))) void*)g,
        (__attribute__((address_space(3))) void*)lds, 16, 0, 0);
}

// ---------------- cast x (fp32 -> bf16) ----------------
__global__ __launch_bounds__(256) void cast_x_kernel(const float* __restrict__ x,
                                                     unsigned short* __restrict__ xb,
                                                     int n4) {
    int i = blockIdx.x * 256 + threadIdx.x;
    if (i >= n4) return;
    float4 v = reinterpret_cast<const float4*>(x)[i];
    ushort4 o;
    o.x = f2bf(v.x); o.y = f2bf(v.y); o.z = f2bf(v.z); o.w = f2bf(v.w);
    reinterpret_cast<ushort4*>(xb)[i] = o;
}

// ---------------- tiled 1024x1024 transpose fp32 -> bf16 ----------------
__global__ __launch_bounds__(256) void transpose_cast_kernel(
    const float* __restrict__ s0, const float* __restrict__ s1,
    const float* __restrict__ s2, const float* __restrict__ s3,
    unsigned short* __restrict__ d0, unsigned short* __restrict__ d1,
    unsigned short* __restrict__ d2, unsigned short* __restrict__ d3) {
    int z = blockIdx.z;
    const float* in = z == 0 ? s0 : z == 1 ? s1 : z == 2 ? s2 : s3;
    unsigned short* out = z == 0 ? d0 : z == 1 ? d1 : z == 2 ? d2 : d3;
    __shared__ float t[64][65];
    int i0 = blockIdx.x * 64, j0 = blockIdx.y * 64;
    int tid = threadIdx.x, r = tid >> 4, c4 = (tid & 15) * 4;
    for (int rr = 0; rr < 4; ++rr) {
        float4 v = *reinterpret_cast<const float4*>(&in[(size_t)(i0 + rr * 16 + r) * 1024 + j0 + c4]);
        t[rr * 16 + r][c4 + 0] = v.x; t[rr * 16 + r][c4 + 1] = v.y;
        t[rr * 16 + r][c4 + 2] = v.z; t[rr * 16 + r][c4 + 3] = v.w;
    }
    __syncthreads();
    for (int rr = 0; rr < 4; ++rr) {
        int orow = rr * 16 + r;
        ushort4 o;
        o.x = f2bf(t[c4 + 0][orow]); o.y = f2bf(t[c4 + 1][orow]);
        o.z = f2bf(t[c4 + 2][orow]); o.w = f2bf(t[c4 + 3][orow]);
        *reinterpret_cast<ushort4*>(&out[(size_t)(j0 + orow) * 1024 + i0 + c4]) = o;
    }
}

// ---------------- GEMM  C[M,N] = A[M,K] * Bt[N,K]^T ----------------
// 128x128 tile, BK=64, global_load_lds staging (m97 structure).
// MODE 0: QKV epilogue (q,k normal [B,H,S,dk]; V TRANSPOSED [B,H,dk,S])
// MODE 1: attn-out epilogue (out = acc + bo + x residual, fp32)
template <int MODE>
__global__ __launch_bounds__(256) void gemm_bt_kernel(
    const unsigned short* __restrict__ A, const unsigned short* __restrict__ Bt,
    int M, int N, int K,
    unsigned short* __restrict__ qb, unsigned short* __restrict__ kb,
    unsigned short* __restrict__ vbT,
    const float* __restrict__ bq, const float* __restrict__ bk,
    const float* __restrict__ bv,
    const float* __restrict__ xres, const float* __restrict__ bo,
    float* __restrict__ out) {
    __shared__ unsigned short Al[128 * 64];
    __shared__ unsigned short Bl[128 * 64];
    int tid = threadIdx.x;
    int m0 = blockIdx.y * 128, n0 = blockIdx.x * 128;
    int w = tid >> 6, l = tid & 63, g = l >> 4, lr = l & 15;
    int wr = (w >> 1) * 64, wc = (w & 1) * 64;
    int srow = tid >> 3, scol = (tid & 7) * 8;
    unsigned short* AlW = Al + w * 512;  // wave-uniform LDS base
    unsigned short* BlW = Bl + w * 512;
    f32x4 acc[4][4];
    for (int i = 0; i < 4; ++i)
        for (int j = 0; j < 4; ++j)
            for (int e = 0; e < 4; ++e) acc[i][j][e] = 0.0f;

    for (int k0 = 0; k0 < K; k0 += 64) {
        const unsigned short* Ap = A + (size_t)(m0 + srow) * K + k0 + scol;
        const unsigned short* Bp = Bt + (size_t)(n0 + srow) * K + k0 + scol;
        for (int i = 0; i < 4; ++i) gload16(Ap + (size_t)i * 32 * K, AlW + i * 2048);
        for (int i = 0; i < 4; ++i) gload16(Bp + (size_t)i * 32 * K, BlW + i * 2048);
        __syncthreads();
        for (int kk = 0; kk < 64; kk += 32) {
            short8 af[4], bf[4];
            for (int mi = 0; mi < 4; ++mi)
                af[mi] = *reinterpret_cast<const short8*>(&Al[(wr + mi * 16 + lr) * 64 + kk + g * 8]);
            for (int ni = 0; ni < 4; ++ni)
                bf[ni] = *reinterpret_cast<const short8*>(&Bl[(wc + ni * 16 + lr) * 64 + kk + g * 8]);
            for (int mi = 0; mi < 4; ++mi)
                for (int ni = 0; ni < 4; ++ni)
                    acc[mi][ni] = __builtin_amdgcn_mfma_f32_16x16x32_bf16(
                        af[mi], bf[ni], acc[mi][ni], 0, 0, 0);
        }
        __syncthreads();
    }
    for (int mi = 0; mi < 4; ++mi) {
        for (int ni = 0; ni < 4; ++ni) {
            int col = n0 + wc + ni * 16 + lr;
            for (int r = 0; r < 4; ++r) {
                int m = m0 + wr + mi * 16 + g * 4 + r;
                float val = acc[mi][ni][r];
                if (MODE == 0) {
                    int sel = col >> 10, nn = col & 1023;
                    int hh = nn >> 6, kk2 = nn & 63;
                    int bb2 = m >> 11, ss2 = m & 2047;
                    if (sel == 0)
                        qb[(((size_t)bb2 * NH + hh) * S_LEN + ss2) * DK + kk2] = f2bf(val + bq[nn]);
                    else if (sel == 1)
                        kb[(((size_t)bb2 * NH + hh) * S_LEN + ss2) * DK + kk2] = f2bf(val + bk[nn]);
                    else  // V stored transposed: [B,H,dk,S]
                        vbT[(((size_t)bb2 * NH + hh) * DK + kk2) * S_LEN + ss2] = f2bf(val + bv[nn]);
                } else {
                    out[(size_t)m * DMODEL + col] = val + bo[col] + xres[(size_t)m * DMODEL + col];
                }
            }
        }
    }
}

// ---------------- flash attention, causal ----------------
// Block = (b,h,128 Q rows); 4 waves x 32 rows (2 frags). KV tiles of 64.
// K staged [64 kv][64 dk]; V^T staged [64 dk][64 kv] (no transpose needed).
__global__ __launch_bounds__(256, 4) void attn_kernel(const unsigned short* __restrict__ qb,
                                                      const unsigned short* __restrict__ kb,
                                                      const unsigned short* __restrict__ vbT,
                                                      unsigned short* __restrict__ ctx) {
    __shared__ unsigned short Kl[64][72];
    __shared__ unsigned short Vt[64][72];
    __shared__ unsigned short Pl[128][72];
    int qt = blockIdx.x, h = blockIdx.y, b = blockIdx.z;
    int q0 = qt * 128;
    size_t base = ((size_t)b * NH + h) * S_LEN * DK;  // q,k and v^T same size
    int tid = threadIdx.x, w = tid >> 6, l = tid & 63, g = l >> 4, lr = l & 15;
    int r8 = tid >> 3, c8 = (tid & 7) * 8;

    short8 qf[2][2];  // [mi][ks] straight from global
    for (int mi = 0; mi < 2; ++mi)
        for (int ks = 0; ks < 2; ++ks)
            qf[mi][ks] = *reinterpret_cast<const short8*>(
                &qb[base + (size_t)(q0 + w * 32 + mi * 16 + lr) * DK + ks * 32 + g * 8]);

    f32x4 ctxa[2][4];
    for (int mi = 0; mi < 2; ++mi)
        for (int f = 0; f < 4; ++f)
            for (int e = 0; e < 4; ++e) ctxa[mi][f][e] = 0.0f;
    float m_r[2][4], l_r[2][4];
    for (int mi = 0; mi < 2; ++mi)
        for (int r = 0; r < 4; ++r) { m_r[mi][r] = -3e38f; l_r[mi][r] = 0.f; }

    int nt = 2 * qt + 2;
    uint4 kreg[2], vreg[2];
    for (int i = 0; i < 2; ++i) {
        kreg[i] = *reinterpret_cast<const uint4*>(&kb[base + (size_t)(i * 32 + r8) * DK + c8]);
        vreg[i] = *reinterpret_cast<const uint4*>(&vbT[base + (size_t)(i * 32 + r8) * S_LEN + c8]);
    }

    for (int t = 0; t < nt; ++t) {
        int kv0 = t * 64;
        __syncthreads();  // previous tile's LDS reads complete
        for (int i = 0; i < 2; ++i) {
            *reinterpret_cast<uint4*>(&Kl[i * 32 + r8][c8]) = kreg[i];
            *reinterpret_cast<uint4*>(&Vt[i * 32 + r8][c8]) = vreg[i];
        }
        __syncthreads();
        if (t + 1 < nt) {  // T14: prefetch next tile under compute
            int kv1 = kv0 + 64;
            for (int i = 0; i < 2; ++i) {
                kreg[i] = *reinterpret_cast<const uint4*>(
                    &kb[base + (size_t)(kv1 + i * 32 + r8) * DK + c8]);
                vreg[i] = *reinterpret_cast<const uint4*>(
                    &vbT[base + (size_t)(i * 32 + r8) * S_LEN + kv1 + c8]);
            }
        }

        for (int mi = 0; mi < 2; ++mi) {
            f32x4 sc[4];
            for (int f = 0; f < 4; ++f)
                for (int e = 0; e < 4; ++e) sc[f][e] = 0.0f;
            for (int ks = 0; ks < 2; ++ks)
                for (int f = 0; f < 4; ++f) {
                    short8 kf = *reinterpret_cast<const short8*>(&Kl[f * 16 + lr][ks * 32 + g * 8]);
                    sc[f] = __builtin_amdgcn_mfma_f32_16x16x32_bf16(qf[mi][ks], kf, sc[f], 0, 0, 0);
                }
            for (int f = 0; f < 4; ++f)
                for (int r = 0; r < 4; ++r) sc[f][r] *= 0.125f;
            if (t >= 2 * qt) {  // diagonal region: causal mask
                for (int f = 0; f < 4; ++f)
                    for (int r = 0; r < 4; ++r) {
                        int colg = kv0 + f * 16 + lr;
                        int rowg = q0 + w * 32 + mi * 16 + g * 4 + r;
                        if (colg > rowg) sc[f][r] = -3e38f;
                    }
            }
            float tm[4], alpha[4], ts[4];
            for (int r = 0; r < 4; ++r)
                tm[r] = fmaxf(fmaxf(sc[0][r], sc[1][r]), fmaxf(sc[2][r], sc[3][r]));
            for (int mk = 1; mk < 16; mk <<= 1)
                for (int r = 0; r < 4; ++r) tm[r] = fmaxf(tm[r], __shfl_xor(tm[r], mk));
            for (int r = 0; r < 4; ++r) {
                float mn = fmaxf(m_r[mi][r], tm[r]);
                alpha[r] = __expf(m_r[mi][r] - mn);
                m_r[mi][r] = mn;
                l_r[mi][r] *= alpha[r];
                ts[r] = 0.f;
            }
            for (int f = 0; f < 4; ++f)
                for (int r = 0; r < 4; ++r) ctxa[mi][f][r] *= alpha[r];
            for (int f = 0; f < 4; ++f)
                for (int r = 0; r < 4; ++r) {
                    float p = __expf(sc[f][r] - m_r[mi][r]);
                    ts[r] += p;
                    Pl[w * 32 + mi * 16 + g * 4 + r][f * 16 + lr] = f2bf(p);
                }
            for (int mk = 1; mk < 16; mk <<= 1)
                for (int r = 0; r < 4; ++r) ts[r] += __shfl_xor(ts[r], mk);
            for (int r = 0; r < 4; ++r) l_r[mi][r] += ts[r];
        }
        __syncthreads();  // Pl ready
        for (int ks = 0; ks < 2; ++ks) {
            short8 vf[4];
            for (int f = 0; f < 4; ++f)
                vf[f] = *reinterpret_cast<const short8*>(&Vt[f * 16 + lr][ks * 32 + g * 8]);
            for (int mi = 0; mi < 2; ++mi) {
                short8 pa = *reinterpret_cast<const short8*>(&Pl[w * 32 + mi * 16 + lr][ks * 32 + g * 8]);
                for (int f = 0; f < 4; ++f)
                    ctxa[mi][f] = __builtin_amdgcn_mfma_f32_16x16x32_bf16(pa, vf[f], ctxa[mi][f], 0, 0, 0);
            }
        }
    }
    for (int mi = 0; mi < 2; ++mi)
        for (int f = 0; f < 4; ++f)
            for (int r = 0; r < 4; ++r) {
                int s = q0 + w * 32 + mi * 16 + g * 4 + r;
                int d = f * 16 + lr;
                ctx[(((size_t)b * S_LEN + s) * NH + h) * DK + d] = f2bf(ctxa[mi][f][r] / l_r[mi][r]);
            }
}

// ---------------- LayerNorm in-place on d_out ----------------
__global__ __launch_bounds__(256) void ln_kernel(float* __restrict__ y,
                                                 const float* __restrict__ gamma,
                                                 const float* __restrict__ beta) {
    int row = blockIdx.x, tid = threadIdx.x;
    float4 v = reinterpret_cast<const float4*>(y + (size_t)row * DMODEL)[tid];
    float s = v.x + v.y + v.z + v.w;
    float q = v.x * v.x + v.y * v.y + v.z * v.z + v.w * v.w;
    for (int off = 32; off >= 1; off >>= 1) {
        s += __shfl_down(s, off);
        q += __shfl_down(q, off);
    }
    __shared__ float ss[4], sq[4];
    int w = tid >> 6, l = tid & 63;
    if (l == 0) { ss[w] = s; sq[w] = q; }
    __syncthreads();
    s = ss[0] + ss[1] + ss[2] + ss[3];
    q = sq[0] + sq[1] + sq[2] + sq[3];
    float mu = s * (1.0f / 1024.0f);
    float var = q * (1.0f / 1024.0f) - mu * mu;
    float inv = rsqrtf(var + 1e-6f);
    float4 g4 = reinterpret_cast<const float4*>(gamma)[tid];
    float4 b4 = reinterpret_cast<const float4*>(beta)[tid];
    float4 o;
    o.x = (v.x - mu) * inv * g4.x + b4.x;
    o.y = (v.y - mu) * inv * g4.y + b4.y;
    o.z = (v.z - mu) * inv * g4.z + b4.z;
    o.w = (v.w - mu) * inv * g4.w + b4.w;
    reinterpret_cast<float4*>(y + (size_t)row * DMODEL)[tid] = o;
}

extern "C" void kernel_launch(void* const* d_in, const int* in_sizes, int n_in,
                              void* d_out, int out_size, void* d_ws, size_t ws_size,
                              hipStream_t stream) {
    const float* x     = (const float*)d_in[0];
    const float* Wq    = (const float*)d_in[1];
    const float* bq    = (const float*)d_in[2];
    const float* Wk    = (const float*)d_in[3];
    const float* bk    = (const float*)d_in[4];
    const float* Wv    = (const float*)d_in[5];
    const float* bv    = (const float*)d_in[6];
    const float* Wo    = (const float*)d_in[7];
    const float* bo    = (const float*)d_in[8];
    const float* gamma = (const float*)d_in[9];
    const float* beta  = (const float*)d_in[10];
    float* out = (float*)d_out;
    char* ws = (char*)d_ws;
    unsigned short* xbf   = (unsigned short*)(ws);              // 16 MB (reused as ctx)
    unsigned short* wqkvT = (unsigned short*)(ws + 16777216);   // 6 MB  [3072][1024]
    unsigned short* woT   = (unsigned short*)(ws + 23068672);   // 2 MB  [1024][1024]
    unsigned short* qbuf  = (unsigned short*)(ws + 25165824);   // 16 MB [B,H,S,dk]
    unsigned short* kbuf  = (unsigned short*)(ws + 41943040);   // 16 MB [B,H,S,dk]
    unsigned short* vbufT = (unsigned short*)(ws + 58720256);   // 16 MB [B,H,dk,S]
    unsigned short* ctx   = xbf;  // xbf dead after QKV GEMM

    cast_x_kernel<<<8192, 256, 0, stream>>>(x, xbf, 2097152);
    dim3 tg(16, 16, 4);
    transpose_cast_kernel<<<tg, 256, 0, stream>>>(Wq, Wk, Wv, Wo, wqkvT,
                                                  wqkvT + 1048576, wqkvT + 2097152, woT);

    dim3 g1(24, 64);
    gemm_bt_kernel<0><<<g1, 256, 0, stream>>>(xbf, wqkvT, 8192, 3072, 1024,
                                              qbuf, kbuf, vbufT, bq, bk, bv,
                                              nullptr, nullptr, nullptr);
    dim3 ga(16, 16, 4);  // S/128, H, B
    attn_kernel<<<ga, 256, 0, stream>>>(qbuf, kbuf, vbufT, ctx);

    dim3 g2(8, 64);
    gemm_bt_kernel<1><<<g2, 256, 0, stream>>>(ctx, woT, 8192, 1024, 1024,
                                              nullptr, nullptr, nullptr,
                                              nullptr, nullptr, nullptr,
                                              x, bo, out);
    ln_kernel<<<8192, 256, 0, stream>>>(out, gamma, beta);
}

// Round 4
// 415.178 us; speedup vs baseline: 1.6948x; 1.6948x over previous
//
#include <hip/hip_runtime.h>

// Fused causal self-attention block: B=4, S=2048, D=1024, H=16, dk=64.
// cast/transpose -> QKV GEMM (global_load_lds; LDS-bounce epilogue, V stored
// transposed with packed 16B writes) -> flash attention (QBLK=128, paired
// Q-tiles for causal load balance, V^T staged, T14 prefetch) ->
// out GEMM + residual -> LayerNorm.

typedef __attribute__((ext_vector_type(8))) short short8;
typedef __attribute__((ext_vector_type(4))) float f32x4;

#define S_LEN 2048
#define NH 16
#define DK 64
#define DMODEL 1024

__device__ inline unsigned short f2bf(float f) {
    unsigned int u = __builtin_bit_cast(unsigned int, f);
    unsigned int r = (u + 0x7fffu + ((u >> 16) & 1u)) >> 16;  // RNE
    return (unsigned short)r;
}

__device__ inline void gload16(const unsigned short* g, unsigned short* lds) {
    __builtin_amdgcn_global_load_lds(
        (const __attribute__((address_space(1))) void*)g,
        (__attribute__((address_space(3))) void*)lds, 16, 0, 0);
}

// ---------------- cast x (fp32 -> bf16) ----------------
__global__ __launch_bounds__(256) void cast_x_kernel(const float* __restrict__ x,
                                                     unsigned short* __restrict__ xb,
                                                     int n4) {
    int i = blockIdx.x * 256 + threadIdx.x;
    if (i >= n4) return;
    float4 v = reinterpret_cast<const float4*>(x)[i];
    ushort4 o;
    o.x = f2bf(v.x); o.y = f2bf(v.y); o.z = f2bf(v.z); o.w = f2bf(v.w);
    reinterpret_cast<ushort4*>(xb)[i] = o;
}

// ---------------- tiled 1024x1024 transpose fp32 -> bf16 ----------------
__global__ __launch_bounds__(256) void transpose_cast_kernel(
    const float* __restrict__ s0, const float* __restrict__ s1,
    const float* __restrict__ s2, const float* __restrict__ s3,
    unsigned short* __restrict__ d0, unsigned short* __restrict__ d1,
    unsigned short* __restrict__ d2, unsigned short* __restrict__ d3) {
    int z = blockIdx.z;
    const float* in = z == 0 ? s0 : z == 1 ? s1 : z == 2 ? s2 : s3;
    unsigned short* out = z == 0 ? d0 : z == 1 ? d1 : z == 2 ? d2 : d3;
    __shared__ float t[64][65];
    int i0 = blockIdx.x * 64, j0 = blockIdx.y * 64;
    int tid = threadIdx.x, r = tid >> 4, c4 = (tid & 15) * 4;
    for (int rr = 0; rr < 4; ++rr) {
        float4 v = *reinterpret_cast<const float4*>(&in[(size_t)(i0 + rr * 16 + r) * 1024 + j0 + c4]);
        t[rr * 16 + r][c4 + 0] = v.x; t[rr * 16 + r][c4 + 1] = v.y;
        t[rr * 16 + r][c4 + 2] = v.z; t[rr * 16 + r][c4 + 3] = v.w;
    }
    __syncthreads();
    for (int rr = 0; rr < 4; ++rr) {
        int orow = rr * 16 + r;
        ushort4 o;
        o.x = f2bf(t[c4 + 0][orow]); o.y = f2bf(t[c4 + 1][orow]);
        o.z = f2bf(t[c4 + 2][orow]); o.w = f2bf(t[c4 + 3][orow]);
        *reinterpret_cast<ushort4*>(&out[(size_t)(j0 + orow) * 1024 + i0 + c4]) = o;
    }
}

// ---------------- GEMM  C[M,N] = A[M,K] * Bt[N,K]^T ----------------
// 128x128 tile, BK=64, global_load_lds staging (m97 structure).
// MODE 0: QKV epilogue via LDS bounce -> packed 16B stores.
//         q,k normal [B,H,S,dk]; V TRANSPOSED [B,H,dk,S].
// MODE 1: attn-out epilogue (out = acc + bo + x residual, fp32, coalesced)
template <int MODE>
__global__ __launch_bounds__(256) void gemm_bt_kernel(
    const unsigned short* __restrict__ A, const unsigned short* __restrict__ Bt,
    int M, int N, int K,
    unsigned short* __restrict__ qb, unsigned short* __restrict__ kb,
    unsigned short* __restrict__ vbT,
    const float* __restrict__ bq, const float* __restrict__ bk,
    const float* __restrict__ bv,
    const float* __restrict__ xres, const float* __restrict__ bo,
    float* __restrict__ out) {
    __shared__ unsigned short smem[17408];  // Al(8192) + Bl(8192) | Ct(128x136)
    unsigned short* Al = smem;
    unsigned short* Bl = smem + 8192;
    unsigned short* Ct = smem;
    int tid = threadIdx.x;
    int m0 = blockIdx.y * 128, n0 = blockIdx.x * 128;
    int w = tid >> 6, l = tid & 63, g = l >> 4, lr = l & 15;
    int wr = (w >> 1) * 64, wc = (w & 1) * 64;
    int srow = tid >> 3, scol = (tid & 7) * 8;
    unsigned short* AlW = Al + w * 512;  // wave-uniform LDS base
    unsigned short* BlW = Bl + w * 512;
    f32x4 acc[4][4];
    for (int i = 0; i < 4; ++i)
        for (int j = 0; j < 4; ++j)
            for (int e = 0; e < 4; ++e) acc[i][j][e] = 0.0f;

    for (int k0 = 0; k0 < K; k0 += 64) {
        const unsigned short* Ap = A + (size_t)(m0 + srow) * K + k0 + scol;
        const unsigned short* Bp = Bt + (size_t)(n0 + srow) * K + k0 + scol;
        for (int i = 0; i < 4; ++i) gload16(Ap + (size_t)i * 32 * K, AlW + i * 2048);
        for (int i = 0; i < 4; ++i) gload16(Bp + (size_t)i * 32 * K, BlW + i * 2048);
        __syncthreads();
        for (int kk = 0; kk < 64; kk += 32) {
            short8 af[4], bf[4];
            for (int mi = 0; mi < 4; ++mi)
                af[mi] = *reinterpret_cast<const short8*>(&Al[(wr + mi * 16 + lr) * 64 + kk + g * 8]);
            for (int ni = 0; ni < 4; ++ni)
                bf[ni] = *reinterpret_cast<const short8*>(&Bl[(wc + ni * 16 + lr) * 64 + kk + g * 8]);
            for (int mi = 0; mi < 4; ++mi)
                for (int ni = 0; ni < 4; ++ni)
                    acc[mi][ni] = __builtin_amdgcn_mfma_f32_16x16x32_bf16(
                        af[mi], bf[ni], acc[mi][ni], 0, 0, 0);
        }
        __syncthreads();
    }

    if (MODE == 0) {
        // Stage tile into LDS (bias added, bf16), V-blocks transposed.
        bool isv = (n0 >= 2048);
        const float* bias = (n0 < 1024) ? bq : (n0 < 2048) ? bk : bv;
        int nb = n0 & 1023;
        for (int mi = 0; mi < 4; ++mi)
            for (int ni = 0; ni < 4; ++ni) {
                int cl = wc + ni * 16 + lr;
                for (int r = 0; r < 4; ++r) {
                    int ml = wr + mi * 16 + g * 4 + r;
                    unsigned short bfv = f2bf(acc[mi][ni][r] + bias[nb + cl]);
                    if (isv) Ct[cl * 136 + ml] = bfv;
                    else     Ct[ml * 136 + cl] = bfv;
                }
            }
        __syncthreads();
        // Cooperative packed write-out: 16 chunks x 128 rows of short8.
        int chunk = tid & 15, rowb = tid >> 4;
        int bb = m0 >> 11, s0 = m0 & 2047;
        for (int it = 0; it < 8; ++it) {
            int rr = it * 16 + rowb;
            short8 vd = *reinterpret_cast<const short8*>(&Ct[rr * 136 + chunk * 8]);
            if (isv) {
                int nn = nb + rr, hh = nn >> 6, kk2 = nn & 63;
                *reinterpret_cast<short8*>(
                    &vbT[(((size_t)bb * NH + hh) * DK + kk2) * S_LEN + s0 + chunk * 8]) = vd;
            } else {
                int nn = nb + chunk * 8, hh = nn >> 6, kk2 = nn & 63;
                unsigned short* dst = (n0 < 1024) ? qb : kb;
                *reinterpret_cast<short8*>(
                    &dst[(((size_t)bb * NH + hh) * S_LEN + s0 + rr) * DK + kk2]) = vd;
            }
        }
    } else {
        for (int mi = 0; mi < 4; ++mi)
            for (int ni = 0; ni < 4; ++ni) {
                int col = n0 + wc + ni * 16 + lr;
                for (int r = 0; r < 4; ++r) {
                    int m = m0 + wr + mi * 16 + g * 4 + r;
                    out[(size_t)m * DMODEL + col] =
                        acc[mi][ni][r] + bo[col] + xres[(size_t)m * DMODEL + col];
                }
            }
    }
}

// ---------------- flash attention, causal ----------------
// Block = (b,h, paired Q-tiles {qt, 15-qt}) -> uniform 34 KV-tiles/block.
// 4 waves x 32 rows (2 frags). K staged [64 kv][64 dk]; V^T staged [64 dk][64 kv].
__global__ __launch_bounds__(256, 4) void attn_kernel(const unsigned short* __restrict__ qb,
                                                      const unsigned short* __restrict__ kb,
                                                      const unsigned short* __restrict__ vbT,
                                                      unsigned short* __restrict__ ctx) {
    __shared__ unsigned short Kl[64][72];
    __shared__ unsigned short Vt[64][72];
    __shared__ unsigned short Pl[128][72];
    int h = blockIdx.y, b = blockIdx.z;
    size_t base = ((size_t)b * NH + h) * S_LEN * DK;
    int tid = threadIdx.x, w = tid >> 6, l = tid & 63, g = l >> 4, lr = l & 15;
    int r8 = tid >> 3, c8 = (tid & 7) * 8;

    for (int seg = 0; seg < 2; ++seg) {
        int qt = seg == 0 ? blockIdx.x : 15 - blockIdx.x;
        int q0 = qt * 128;

        short8 qf[2][2];
        for (int mi = 0; mi < 2; ++mi)
            for (int ks = 0; ks < 2; ++ks)
                qf[mi][ks] = *reinterpret_cast<const short8*>(
                    &qb[base + (size_t)(q0 + w * 32 + mi * 16 + lr) * DK + ks * 32 + g * 8]);

        f32x4 ctxa[2][4];
        for (int mi = 0; mi < 2; ++mi)
            for (int f = 0; f < 4; ++f)
                for (int e = 0; e < 4; ++e) ctxa[mi][f][e] = 0.0f;
        float m_r[2][4], l_r[2][4];
        for (int mi = 0; mi < 2; ++mi)
            for (int r = 0; r < 4; ++r) { m_r[mi][r] = -3e38f; l_r[mi][r] = 0.f; }

        int nt = 2 * qt + 2;
        uint4 kreg[2], vreg[2];
        for (int i = 0; i < 2; ++i) {
            kreg[i] = *reinterpret_cast<const uint4*>(&kb[base + (size_t)(i * 32 + r8) * DK + c8]);
            vreg[i] = *reinterpret_cast<const uint4*>(&vbT[base + (size_t)(i * 32 + r8) * S_LEN + c8]);
        }

        for (int t = 0; t < nt; ++t) {
            int kv0 = t * 64;
            __syncthreads();  // previous tile's LDS reads complete
            for (int i = 0; i < 2; ++i) {
                *reinterpret_cast<uint4*>(&Kl[i * 32 + r8][c8]) = kreg[i];
                *reinterpret_cast<uint4*>(&Vt[i * 32 + r8][c8]) = vreg[i];
            }
            __syncthreads();
            if (t + 1 < nt) {  // T14: prefetch next tile under compute
                int kv1 = kv0 + 64;
                for (int i = 0; i < 2; ++i) {
                    kreg[i] = *reinterpret_cast<const uint4*>(
                        &kb[base + (size_t)(kv1 + i * 32 + r8) * DK + c8]);
                    vreg[i] = *reinterpret_cast<const uint4*>(
                        &vbT[base + (size_t)(i * 32 + r8) * S_LEN + kv1 + c8]);
                }
            }

            for (int mi = 0; mi < 2; ++mi) {
                f32x4 sc[4];
                for (int f = 0; f < 4; ++f)
                    for (int e = 0; e < 4; ++e) sc[f][e] = 0.0f;
                for (int ks = 0; ks < 2; ++ks)
                    for (int f = 0; f < 4; ++f) {
                        short8 kf = *reinterpret_cast<const short8*>(&Kl[f * 16 + lr][ks * 32 + g * 8]);
                        sc[f] = __builtin_amdgcn_mfma_f32_16x16x32_bf16(qf[mi][ks], kf, sc[f], 0, 0, 0);
                    }
                for (int f = 0; f < 4; ++f)
                    for (int r = 0; r < 4; ++r) sc[f][r] *= 0.125f;
                if (t >= 2 * qt) {  // diagonal region: causal mask
                    for (int f = 0; f < 4; ++f)
                        for (int r = 0; r < 4; ++r) {
                            int colg = kv0 + f * 16 + lr;
                            int rowg = q0 + w * 32 + mi * 16 + g * 4 + r;
                            if (colg > rowg) sc[f][r] = -3e38f;
                        }
                }
                float tm[4], alpha[4], ts[4];
                for (int r = 0; r < 4; ++r)
                    tm[r] = fmaxf(fmaxf(sc[0][r], sc[1][r]), fmaxf(sc[2][r], sc[3][r]));
                for (int mk = 1; mk < 16; mk <<= 1)
                    for (int r = 0; r < 4; ++r) tm[r] = fmaxf(tm[r], __shfl_xor(tm[r], mk));
                for (int r = 0; r < 4; ++r) {
                    float mn = fmaxf(m_r[mi][r], tm[r]);
                    alpha[r] = __expf(m_r[mi][r] - mn);
                    m_r[mi][r] = mn;
                    l_r[mi][r] *= alpha[r];
                    ts[r] = 0.f;
                }
                for (int f = 0; f < 4; ++f)
                    for (int r = 0; r < 4; ++r) ctxa[mi][f][r] *= alpha[r];
                for (int f = 0; f < 4; ++f)
                    for (int r = 0; r < 4; ++r) {
                        float p = __expf(sc[f][r] - m_r[mi][r]);
                        ts[r] += p;
                        Pl[w * 32 + mi * 16 + g * 4 + r][f * 16 + lr] = f2bf(p);
                    }
                for (int mk = 1; mk < 16; mk <<= 1)
                    for (int r = 0; r < 4; ++r) ts[r] += __shfl_xor(ts[r], mk);
                for (int r = 0; r < 4; ++r) l_r[mi][r] += ts[r];
            }
            __syncthreads();  // Pl ready
            for (int ks = 0; ks < 2; ++ks) {
                short8 vf[4];
                for (int f = 0; f < 4; ++f)
                    vf[f] = *reinterpret_cast<const short8*>(&Vt[f * 16 + lr][ks * 32 + g * 8]);
                for (int mi = 0; mi < 2; ++mi) {
                    short8 pa = *reinterpret_cast<const short8*>(&Pl[w * 32 + mi * 16 + lr][ks * 32 + g * 8]);
                    for (int f = 0; f < 4; ++f)
                        ctxa[mi][f] = __builtin_amdgcn_mfma_f32_16x16x32_bf16(pa, vf[f], ctxa[mi][f], 0, 0, 0);
                }
            }
        }
        for (int mi = 0; mi < 2; ++mi)
            for (int f = 0; f < 4; ++f)
                for (int r = 0; r < 4; ++r) {
                    int s = q0 + w * 32 + mi * 16 + g * 4 + r;
                    int d = f * 16 + lr;
                    ctx[(((size_t)b * S_LEN + s) * NH + h) * DK + d] = f2bf(ctxa[mi][f][r] / l_r[mi][r]);
                }
        __syncthreads();  // K/V LDS reuse across segments
    }
}

// ---------------- LayerNorm in-place on d_out ----------------
__global__ __launch_bounds__(256) void ln_kernel(float* __restrict__ y,
                                                 const float* __restrict__ gamma,
                                                 const float* __restrict__ beta) {
    int row = blockIdx.x, tid = threadIdx.x;
    float4 v = reinterpret_cast<const float4*>(y + (size_t)row * DMODEL)[tid];
    float s = v.x + v.y + v.z + v.w;
    float q = v.x * v.x + v.y * v.y + v.z * v.z + v.w * v.w;
    for (int off = 32; off >= 1; off >>= 1) {
        s += __shfl_down(s, off);
        q += __shfl_down(q, off);
    }
    __shared__ float ss[4], sq[4];
    int w = tid >> 6, l = tid & 63;
    if (l == 0) { ss[w] = s; sq[w] = q; }
    __syncthreads();
    s = ss[0] + ss[1] + ss[2] + ss[3];
    q = sq[0] + sq[1] + sq[2] + sq[3];
    float mu = s * (1.0f / 1024.0f);
    float var = q * (1.0f / 1024.0f) - mu * mu;
    float inv = rsqrtf(var + 1e-6f);
    float4 g4 = reinterpret_cast<const float4*>(gamma)[tid];
    float4 b4 = reinterpret_cast<const float4*>(beta)[tid];
    float4 o;
    o.x = (v.x - mu) * inv * g4.x + b4.x;
    o.y = (v.y - mu) * inv * g4.y + b4.y;
    o.z = (v.z - mu) * inv * g4.z + b4.z;
    o.w = (v.w - mu) * inv * g4.w + b4.w;
    reinterpret_cast<float4*>(y + (size_t)row * DMODEL)[tid] = o;
}

extern "C" void kernel_launch(void* const* d_in, const int* in_sizes, int n_in,
                              void* d_out, int out_size, void* d_ws, size_t ws_size,
                              hipStream_t stream) {
    const float* x     = (const float*)d_in[0];
    const float* Wq    = (const float*)d_in[1];
    const float* bq    = (const float*)d_in[2];
    const float* Wk    = (const float*)d_in[3];
    const float* bk    = (const float*)d_in[4];
    const float* Wv    = (const float*)d_in[5];
    const float* bv    = (const float*)d_in[6];
    const float* Wo    = (const float*)d_in[7];
    const float* bo    = (const float*)d_in[8];
    const float* gamma = (const float*)d_in[9];
    const float* beta  = (const float*)d_in[10];
    float* out = (float*)d_out;
    char* ws = (char*)d_ws;
    unsigned short* xbf   = (unsigned short*)(ws);              // 16 MB (reused as ctx)
    unsigned short* wqkvT = (unsigned short*)(ws + 16777216);   // 6 MB  [3072][1024]
    unsigned short* woT   = (unsigned short*)(ws + 23068672);   // 2 MB  [1024][1024]
    unsigned short* qbuf  = (unsigned short*)(ws + 25165824);   // 16 MB [B,H,S,dk]
    unsigned short* kbuf  = (unsigned short*)(ws + 41943040);   // 16 MB [B,H,S,dk]
    unsigned short* vbufT = (unsigned short*)(ws + 58720256);   // 16 MB [B,H,dk,S]
    unsigned short* ctx   = xbf;  // xbf dead after QKV GEMM

    cast_x_kernel<<<8192, 256, 0, stream>>>(x, xbf, 2097152);
    dim3 tg(16, 16, 4);
    transpose_cast_kernel<<<tg, 256, 0, stream>>>(Wq, Wk, Wv, Wo, wqkvT,
                                                  wqkvT + 1048576, wqkvT + 2097152, woT);

    dim3 g1(24, 64);
    gemm_bt_kernel<0><<<g1, 256, 0, stream>>>(xbf, wqkvT, 8192, 3072, 1024,
                                              qbuf, kbuf, vbufT, bq, bk, bv,
                                              nullptr, nullptr, nullptr);
    dim3 ga(8, 16, 4);  // paired Q-tiles: {qt, 15-qt}
    attn_kernel<<<ga, 256, 0, stream>>>(qbuf, kbuf, vbufT, ctx);

    dim3 g2(8, 64);
    gemm_bt_kernel<1><<<g2, 256, 0, stream>>>(ctx, woT, 8192, 1024, 1024,
                                              nullptr, nullptr, nullptr,
                                              nullptr, nullptr, nullptr,
                                              x, bo, out);
    ln_kernel<<<8192, 256, 0, stream>>>(out, gamma, beta);
}

// Round 8
// 413.069 us; speedup vs baseline: 1.7034x; 1.0051x over previous
//
#include <hip/hip_runtime.h>

// Fused causal self-attention block: B=4, S=2048, D=1024, H=16, dk=64.
// cast/transpose -> QKV GEMM (global_load_lds; LDS-bounce epilogue, q pre-scaled
// by 0.125*log2e, V stored transposed) -> flash attention (QBLK=64, paired
// Q-tiles, exp2 softmax, defer-max, deferred l-reduce, setprio) ->
// out GEMM + residual -> LayerNorm.

typedef __attribute__((ext_vector_type(8))) short short8;
typedef __attribute__((ext_vector_type(4))) float f32x4;

#define S_LEN 2048
#define NH 16
#define DK 64
#define DMODEL 1024
#define QSCALE 0.18033688011112042f  // 0.125 * log2(e)

__device__ inline float fast_exp2(float x) { return __builtin_amdgcn_exp2f(x); }

__device__ inline unsigned short f2bf(float f) {
    unsigned int u = __builtin_bit_cast(unsigned int, f);
    unsigned int r = (u + 0x7fffu + ((u >> 16) & 1u)) >> 16;  // RNE
    return (unsigned short)r;
}

__device__ inline void gload16(const unsigned short* g, unsigned short* lds) {
    __builtin_amdgcn_global_load_lds(
        (const __attribute__((address_space(1))) void*)g,
        (__attribute__((address_space(3))) void*)lds, 16, 0, 0);
}

// ---------------- cast x (fp32 -> bf16) ----------------
__global__ __launch_bounds__(256) void cast_x_kernel(const float* __restrict__ x,
                                                     unsigned short* __restrict__ xb,
                                                     int n4) {
    int i = blockIdx.x * 256 + threadIdx.x;
    if (i >= n4) return;
    float4 v = reinterpret_cast<const float4*>(x)[i];
    ushort4 o;
    o.x = f2bf(v.x); o.y = f2bf(v.y); o.z = f2bf(v.z); o.w = f2bf(v.w);
    reinterpret_cast<ushort4*>(xb)[i] = o;
}

// ---------------- tiled 1024x1024 transpose fp32 -> bf16 ----------------
__global__ __launch_bounds__(256) void transpose_cast_kernel(
    const float* __restrict__ s0, const float* __restrict__ s1,
    const float* __restrict__ s2, const float* __restrict__ s3,
    unsigned short* __restrict__ d0, unsigned short* __restrict__ d1,
    unsigned short* __restrict__ d2, unsigned short* __restrict__ d3) {
    int z = blockIdx.z;
    const float* in = z == 0 ? s0 : z == 1 ? s1 : z == 2 ? s2 : s3;
    unsigned short* out = z == 0 ? d0 : z == 1 ? d1 : z == 2 ? d2 : d3;
    __shared__ float t[64][65];
    int i0 = blockIdx.x * 64, j0 = blockIdx.y * 64;
    int tid = threadIdx.x, r = tid >> 4, c4 = (tid & 15) * 4;
    for (int rr = 0; rr < 4; ++rr) {
        float4 v = *reinterpret_cast<const float4*>(&in[(size_t)(i0 + rr * 16 + r) * 1024 + j0 + c4]);
        t[rr * 16 + r][c4 + 0] = v.x; t[rr * 16 + r][c4 + 1] = v.y;
        t[rr * 16 + r][c4 + 2] = v.z; t[rr * 16 + r][c4 + 3] = v.w;
    }
    __syncthreads();
    for (int rr = 0; rr < 4; ++rr) {
        int orow = rr * 16 + r;
        ushort4 o;
        o.x = f2bf(t[c4 + 0][orow]); o.y = f2bf(t[c4 + 1][orow]);
        o.z = f2bf(t[c4 + 2][orow]); o.w = f2bf(t[c4 + 3][orow]);
        *reinterpret_cast<ushort4*>(&out[(size_t)(j0 + orow) * 1024 + i0 + c4]) = o;
    }
}

// ---------------- GEMM  C[M,N] = A[M,K] * Bt[N,K]^T ----------------
// 128x128 tile, BK=64, global_load_lds staging (m97 structure).
// MODE 0: QKV epilogue via LDS bounce -> packed 16B stores.
//         q (scaled by QSCALE), k normal [B,H,S,dk]; V TRANSPOSED [B,H,dk,S].
// MODE 1: attn-out epilogue (out = acc + bo + x residual, fp32, coalesced)
template <int MODE>
__global__ __launch_bounds__(256) void gemm_bt_kernel(
    const unsigned short* __restrict__ A, const unsigned short* __restrict__ Bt,
    int M, int N, int K,
    unsigned short* __restrict__ qb, unsigned short* __restrict__ kb,
    unsigned short* __restrict__ vbT,
    const float* __restrict__ bq, const float* __restrict__ bk,
    const float* __restrict__ bv,
    const float* __restrict__ xres, const float* __restrict__ bo,
    float* __restrict__ out) {
    __shared__ unsigned short smem[17408];  // Al(8192) + Bl(8192) | Ct(128x136)
    unsigned short* Al = smem;
    unsigned short* Bl = smem + 8192;
    unsigned short* Ct = smem;
    int tid = threadIdx.x;
    int m0 = blockIdx.y * 128, n0 = blockIdx.x * 128;
    int w = tid >> 6, l = tid & 63, g = l >> 4, lr = l & 15;
    int wr = (w >> 1) * 64, wc = (w & 1) * 64;
    int srow = tid >> 3, scol = (tid & 7) * 8;
    unsigned short* AlW = Al + w * 512;  // wave-uniform LDS base
    unsigned short* BlW = Bl + w * 512;
    f32x4 acc[4][4];
    for (int i = 0; i < 4; ++i)
        for (int j = 0; j < 4; ++j)
            for (int e = 0; e < 4; ++e) acc[i][j][e] = 0.0f;

    for (int k0 = 0; k0 < K; k0 += 64) {
        const unsigned short* Ap = A + (size_t)(m0 + srow) * K + k0 + scol;
        const unsigned short* Bp = Bt + (size_t)(n0 + srow) * K + k0 + scol;
        for (int i = 0; i < 4; ++i) gload16(Ap + (size_t)i * 32 * K, AlW + i * 2048);
        for (int i = 0; i < 4; ++i) gload16(Bp + (size_t)i * 32 * K, BlW + i * 2048);
        __syncthreads();
        for (int kk = 0; kk < 64; kk += 32) {
            short8 af[4], bf[4];
            for (int mi = 0; mi < 4; ++mi)
                af[mi] = *reinterpret_cast<const short8*>(&Al[(wr + mi * 16 + lr) * 64 + kk + g * 8]);
            for (int ni = 0; ni < 4; ++ni)
                bf[ni] = *reinterpret_cast<const short8*>(&Bl[(wc + ni * 16 + lr) * 64 + kk + g * 8]);
            for (int mi = 0; mi < 4; ++mi)
                for (int ni = 0; ni < 4; ++ni)
                    acc[mi][ni] = __builtin_amdgcn_mfma_f32_16x16x32_bf16(
                        af[mi], bf[ni], acc[mi][ni], 0, 0, 0);
        }
        __syncthreads();
    }

    if (MODE == 0) {
        // Stage tile into LDS (bias added, bf16), V-blocks transposed.
        bool isv = (n0 >= 2048);
        bool isq = (n0 < 1024);
        const float* bias = isq ? bq : (n0 < 2048) ? bk : bv;
        int nb = n0 & 1023;
        for (int mi = 0; mi < 4; ++mi)
            for (int ni = 0; ni < 4; ++ni) {
                int cl = wc + ni * 16 + lr;
                for (int r = 0; r < 4; ++r) {
                    int ml = wr + mi * 16 + g * 4 + r;
                    float vv = acc[mi][ni][r] + bias[nb + cl];
                    if (isq) vv *= QSCALE;  // fold softmax scale + log2e into q
                    unsigned short bfv = f2bf(vv);
                    if (isv) Ct[cl * 136 + ml] = bfv;
                    else     Ct[ml * 136 + cl] = bfv;
                }
            }
        __syncthreads();
        // Cooperative packed write-out: 16 chunks x 128 rows of short8.
        int chunk = tid & 15, rowb = tid >> 4;
        int bb = m0 >> 11, s0 = m0 & 2047;
        for (int it = 0; it < 8; ++it) {
            int rr = it * 16 + rowb;
            short8 vd = *reinterpret_cast<const short8*>(&Ct[rr * 136 + chunk * 8]);
            if (isv) {
                int nn = nb + rr, hh = nn >> 6, kk2 = nn & 63;
                *reinterpret_cast<short8*>(
                    &vbT[(((size_t)bb * NH + hh) * DK + kk2) * S_LEN + s0 + chunk * 8]) = vd;
            } else {
                int nn = nb + chunk * 8, hh = nn >> 6, kk2 = nn & 63;
                unsigned short* dst = isq ? qb : kb;
                *reinterpret_cast<short8*>(
                    &dst[(((size_t)bb * NH + hh) * S_LEN + s0 + rr) * DK + kk2]) = vd;
            }
        }
    } else {
        for (int mi = 0; mi < 4; ++mi)
            for (int ni = 0; ni < 4; ++ni) {
                int col = n0 + wc + ni * 16 + lr;
                for (int r = 0; r < 4; ++r) {
                    int m = m0 + wr + mi * 16 + g * 4 + r;
                    out[(size_t)m * DMODEL + col] =
                        acc[mi][ni][r] + bo[col] + xres[(size_t)m * DMODEL + col];
                }
            }
    }
}

// ---------------- flash attention, causal ----------------
// Block = (b,h, paired Q-tiles {qt, 31-qt}), QBLK=64 -> uniform 33 KV-tiles.
// 4 waves x 16 rows. K staged [64 kv][64 dk]; V^T staged [64 dk][64 kv].
// exp2-domain softmax (q pre-scaled); defer-max (THR=8 in log2 domain);
// l-sum reduced once per segment.
__global__ __launch_bounds__(256, 4) void attn_kernel(const unsigned short* __restrict__ qb,
                                                      const unsigned short* __restrict__ kb,
                                                      const unsigned short* __restrict__ vbT,
                                                      unsigned short* __restrict__ ctx) {
    __shared__ unsigned short Kl[64][72];
    __shared__ unsigned short Vt[64][72];
    __shared__ unsigned short Pl[64][72];
    int pair = blockIdx.x, h = blockIdx.y, b = blockIdx.z;
    size_t base = ((size_t)b * NH + h) * S_LEN * DK;
    int tid = threadIdx.x, w = tid >> 6, l = tid & 63, g = l >> 4, lr = l & 15;
    int r8 = tid >> 3, c8 = (tid & 7) * 8;

    uint4 kreg[2], vreg[2];
    for (int i = 0; i < 2; ++i) {
        kreg[i] = *reinterpret_cast<const uint4*>(&kb[base + (size_t)(i * 32 + r8) * DK + c8]);
        vreg[i] = *reinterpret_cast<const uint4*>(&vbT[base + (size_t)(i * 32 + r8) * S_LEN + c8]);
    }

    for (int seg = 0; seg < 2; ++seg) {
        int qt = seg ? 31 - pair : pair;
        int q0 = qt * 64, nt = qt + 1;

        short8 qf[2];
        for (int ks = 0; ks < 2; ++ks)
            qf[ks] = *reinterpret_cast<const short8*>(
                &qb[base + (size_t)(q0 + w * 16 + lr) * DK + ks * 32 + g * 8]);

        f32x4 ctxa[4];
        for (int f = 0; f < 4; ++f)
            for (int e = 0; e < 4; ++e) ctxa[f][e] = 0.0f;
        float m_r[4], lsum[4];
        for (int r = 0; r < 4; ++r) { m_r[r] = -3e38f; lsum[r] = 0.f; }

        for (int t = 0; t < nt; ++t) {
            int kv0 = t * 64;
            __syncthreads();  // previous tile's LDS reads complete
            for (int i = 0; i < 2; ++i) {
                *reinterpret_cast<uint4*>(&Kl[i * 32 + r8][c8]) = kreg[i];
                *reinterpret_cast<uint4*>(&Vt[i * 32 + r8][c8]) = vreg[i];
            }
            __syncthreads();
            {  // prefetch next tile (or tile 0 of next seg) under compute
                int nkv = (t + 1 < nt) ? kv0 + 64 : 0;
                for (int i = 0; i < 2; ++i) {
                    kreg[i] = *reinterpret_cast<const uint4*>(
                        &kb[base + (size_t)(nkv + i * 32 + r8) * DK + c8]);
                    vreg[i] = *reinterpret_cast<const uint4*>(
                        &vbT[base + (size_t)(i * 32 + r8) * S_LEN + nkv + c8]);
                }
            }

            f32x4 sc[4];
            for (int f = 0; f < 4; ++f)
                for (int e = 0; e < 4; ++e) sc[f][e] = 0.0f;
            __builtin_amdgcn_s_setprio(1);
            for (int ks = 0; ks < 2; ++ks)
                for (int f = 0; f < 4; ++f) {
                    short8 kf = *reinterpret_cast<const short8*>(&Kl[f * 16 + lr][ks * 32 + g * 8]);
                    sc[f] = __builtin_amdgcn_mfma_f32_16x16x32_bf16(qf[ks], kf, sc[f], 0, 0, 0);
                }
            __builtin_amdgcn_s_setprio(0);
            if (t == nt - 1) {  // diagonal tile: causal mask
                for (int f = 0; f < 4; ++f)
                    for (int r = 0; r < 4; ++r) {
                        int colg = kv0 + f * 16 + lr;
                        int rowg = q0 + w * 16 + g * 4 + r;
                        if (colg > rowg) sc[f][r] = -3e38f;
                    }
            }
            float tm[4];
            for (int r = 0; r < 4; ++r)
                tm[r] = fmaxf(fmaxf(sc[0][r], sc[1][r]), fmaxf(sc[2][r], sc[3][r]));
            bool ok = tm[0] <= m_r[0] + 8.f && tm[1] <= m_r[1] + 8.f &&
                      tm[2] <= m_r[2] + 8.f && tm[3] <= m_r[3] + 8.f;
            if (!__all((int)ok)) {  // rescale path (rare after warm-up)
                for (int mk = 1; mk < 16; mk <<= 1)
                    for (int r = 0; r < 4; ++r) tm[r] = fmaxf(tm[r], __shfl_xor(tm[r], mk));
                for (int r = 0; r < 4; ++r) {
                    float mn = fmaxf(m_r[r], tm[r]);
                    float al = fast_exp2(m_r[r] - mn);
                    m_r[r] = mn;
                    lsum[r] *= al;
                    for (int f = 0; f < 4; ++f) ctxa[f][r] *= al;
                }
            }
            for (int f = 0; f < 4; ++f)
                for (int r = 0; r < 4; ++r) {
                    float p = fast_exp2(sc[f][r] - m_r[r]);
                    lsum[r] += p;
                    Pl[w * 16 + g * 4 + r][f * 16 + lr] = f2bf(p);
                }
            __syncthreads();  // Pl ready
            __builtin_amdgcn_s_setprio(1);
            for (int ks = 0; ks < 2; ++ks) {
                short8 pa = *reinterpret_cast<const short8*>(&Pl[w * 16 + lr][ks * 32 + g * 8]);
                for (int f = 0; f < 4; ++f) {
                    short8 vf = *reinterpret_cast<const short8*>(&Vt[f * 16 + lr][ks * 32 + g * 8]);
                    ctxa[f] = __builtin_amdgcn_mfma_f32_16x16x32_bf16(pa, vf, ctxa[f], 0, 0, 0);
                }
            }
            __builtin_amdgcn_s_setprio(0);
        }
        // deferred l reduction (once per segment)
        for (int mk = 1; mk < 16; mk <<= 1)
            for (int r = 0; r < 4; ++r) lsum[r] += __shfl_xor(lsum[r], mk);
        float inv[4];
        for (int r = 0; r < 4; ++r) inv[r] = 1.0f / lsum[r];
        for (int f = 0; f < 4; ++f)
            for (int r = 0; r < 4; ++r) {
                int s = q0 + w * 16 + g * 4 + r;
                int d = f * 16 + lr;
                ctx[(((size_t)b * S_LEN + s) * NH + h) * DK + d] = f2bf(ctxa[f][r] * inv[r]);
            }
    }
}

// ---------------- LayerNorm in-place on d_out ----------------
__global__ __launch_bounds__(256) void ln_kernel(float* __restrict__ y,
                                                 const float* __restrict__ gamma,
                                                 const float* __restrict__ beta) {
    int row = blockIdx.x, tid = threadIdx.x;
    float4 v = reinterpret_cast<const float4*>(y + (size_t)row * DMODEL)[tid];
    float s = v.x + v.y + v.z + v.w;
    float q = v.x * v.x + v.y * v.y + v.z * v.z + v.w * v.w;
    for (int off = 32; off >= 1; off >>= 1) {
        s += __shfl_down(s, off);
        q += __shfl_down(q, off);
    }
    __shared__ float ss[4], sq[4];
    int w = tid >> 6, l = tid & 63;
    if (l == 0) { ss[w] = s; sq[w] = q; }
    __syncthreads();
    s = ss[0] + ss[1] + ss[2] + ss[3];
    q = sq[0] + sq[1] + sq[2] + sq[3];
    float mu = s * (1.0f / 1024.0f);
    float var = q * (1.0f / 1024.0f) - mu * mu;
    float inv = rsqrtf(var + 1e-6f);
    float4 g4 = reinterpret_cast<const float4*>(gamma)[tid];
    float4 b4 = reinterpret_cast<const float4*>(beta)[tid];
    float4 o;
    o.x = (v.x - mu) * inv * g4.x + b4.x;
    o.y = (v.y - mu) * inv * g4.y + b4.y;
    o.z = (v.z - mu) * inv * g4.z + b4.z;
    o.w = (v.w - mu) * inv * g4.w + b4.w;
    reinterpret_cast<float4*>(y + (size_t)row * DMODEL)[tid] = o;
}

extern "C" void kernel_launch(void* const* d_in, const int* in_sizes, int n_in,
                              void* d_out, int out_size, void* d_ws, size_t ws_size,
                              hipStream_t stream) {
    const float* x     = (const float*)d_in[0];
    const float* Wq    = (const float*)d_in[1];
    const float* bq    = (const float*)d_in[2];
    const float* Wk    = (const float*)d_in[3];
    const float* bk    = (const float*)d_in[4];
    const float* Wv    = (const float*)d_in[5];
    const float* bv    = (const float*)d_in[6];
    const float* Wo    = (const float*)d_in[7];
    const float* bo    = (const float*)d_in[8];
    const float* gamma = (const float*)d_in[9];
    const float* beta  = (const float*)d_in[10];
    float* out = (float*)d_out;
    char* ws = (char*)d_ws;
    unsigned short* xbf   = (unsigned short*)(ws);              // 16 MB (reused as ctx)
    unsigned short* wqkvT = (unsigned short*)(ws + 16777216);   // 6 MB  [3072][1024]
    unsigned short* woT   = (unsigned short*)(ws + 23068672);   // 2 MB  [1024][1024]
    unsigned short* qbuf  = (unsigned short*)(ws + 25165824);   // 16 MB [B,H,S,dk] (pre-scaled)
    unsigned short* kbuf  = (unsigned short*)(ws + 41943040);   // 16 MB [B,H,S,dk]
    unsigned short* vbufT = (unsigned short*)(ws + 58720256);   // 16 MB [B,H,dk,S]
    unsigned short* ctx   = xbf;  // xbf dead after QKV GEMM

    cast_x_kernel<<<8192, 256, 0, stream>>>(x, xbf, 2097152);
    dim3 tg(16, 16, 4);
    transpose_cast_kernel<<<tg, 256, 0, stream>>>(Wq, Wk, Wv, Wo, wqkvT,
                                                  wqkvT + 1048576, wqkvT + 2097152, woT);

    dim3 g1(24, 64);
    gemm_bt_kernel<0><<<g1, 256, 0, stream>>>(xbf, wqkvT, 8192, 3072, 1024,
                                              qbuf, kbuf, vbufT, bq, bk, bv,
                                              nullptr, nullptr, nullptr);
    dim3 ga(16, 16, 4);  // paired Q-tiles: {qt, 31-qt}, QBLK=64
    attn_kernel<<<ga, 256, 0, stream>>>(qbuf, kbuf, vbufT, ctx);

    dim3 g2(8, 64);
    gemm_bt_kernel<1><<<g2, 256, 0, stream>>>(ctx, woT, 8192, 1024, 1024,
                                              nullptr, nullptr, nullptr,
                                              nullptr, nullptr, nullptr,
                                              x, bo, out);
    ln_kernel<<<8192, 256, 0, stream>>>(out, gamma, beta);
}

// Round 9
// 322.154 us; speedup vs baseline: 2.1842x; 1.2822x over previous
//
#include <hip/hip_runtime.h>

// Fused causal self-attention block: B=4, S=2048, D=1024, H=16, dk=64.
// cast/transpose -> QKV GEMM (global_load_lds; LDS-bounce epilogue, q pre-scaled
// by 0.125*log2e, V stored transposed) -> flash attention (512-thr block = both
// paired Q-tiles sharing staged KV, XCD-grouped blocks, 2 barriers/tile) ->
// out GEMM + residual -> LayerNorm.

typedef __attribute__((ext_vector_type(8))) short short8;
typedef __attribute__((ext_vector_type(4))) float f32x4;

#define S_LEN 2048
#define NH 16
#define DK 64
#define DMODEL 1024
#define QSCALE 0.18033688011112042f  // 0.125 * log2(e)

__device__ inline float fast_exp2(float x) { return __builtin_amdgcn_exp2f(x); }

__device__ inline unsigned short f2bf(float f) {
    unsigned int u = __builtin_bit_cast(unsigned int, f);
    unsigned int r = (u + 0x7fffu + ((u >> 16) & 1u)) >> 16;  // RNE
    return (unsigned short)r;
}

__device__ inline void gload16(const unsigned short* g, unsigned short* lds) {
    __builtin_amdgcn_global_load_lds(
        (const __attribute__((address_space(1))) void*)g,
        (__attribute__((address_space(3))) void*)lds, 16, 0, 0);
}

// ---------------- cast x (fp32 -> bf16) ----------------
__global__ __launch_bounds__(256) void cast_x_kernel(const float* __restrict__ x,
                                                     unsigned short* __restrict__ xb,
                                                     int n4) {
    int i = blockIdx.x * 256 + threadIdx.x;
    if (i >= n4) return;
    float4 v = reinterpret_cast<const float4*>(x)[i];
    ushort4 o;
    o.x = f2bf(v.x); o.y = f2bf(v.y); o.z = f2bf(v.z); o.w = f2bf(v.w);
    reinterpret_cast<ushort4*>(xb)[i] = o;
}

// ---------------- tiled 1024x1024 transpose fp32 -> bf16 ----------------
__global__ __launch_bounds__(256) void transpose_cast_kernel(
    const float* __restrict__ s0, const float* __restrict__ s1,
    const float* __restrict__ s2, const float* __restrict__ s3,
    unsigned short* __restrict__ d0, unsigned short* __restrict__ d1,
    unsigned short* __restrict__ d2, unsigned short* __restrict__ d3) {
    int z = blockIdx.z;
    const float* in = z == 0 ? s0 : z == 1 ? s1 : z == 2 ? s2 : s3;
    unsigned short* out = z == 0 ? d0 : z == 1 ? d1 : z == 2 ? d2 : d3;
    __shared__ float t[64][65];
    int i0 = blockIdx.x * 64, j0 = blockIdx.y * 64;
    int tid = threadIdx.x, r = tid >> 4, c4 = (tid & 15) * 4;
    for (int rr = 0; rr < 4; ++rr) {
        float4 v = *reinterpret_cast<const float4*>(&in[(size_t)(i0 + rr * 16 + r) * 1024 + j0 + c4]);
        t[rr * 16 + r][c4 + 0] = v.x; t[rr * 16 + r][c4 + 1] = v.y;
        t[rr * 16 + r][c4 + 2] = v.z; t[rr * 16 + r][c4 + 3] = v.w;
    }
    __syncthreads();
    for (int rr = 0; rr < 4; ++rr) {
        int orow = rr * 16 + r;
        ushort4 o;
        o.x = f2bf(t[c4 + 0][orow]); o.y = f2bf(t[c4 + 1][orow]);
        o.z = f2bf(t[c4 + 2][orow]); o.w = f2bf(t[c4 + 3][orow]);
        *reinterpret_cast<ushort4*>(&out[(size_t)(j0 + orow) * 1024 + i0 + c4]) = o;
    }
}

// ---------------- GEMM  C[M,N] = A[M,K] * Bt[N,K]^T ----------------
// 128x128 tile, BK=64, global_load_lds staging (m97 structure).
// MODE 0: QKV epilogue via LDS bounce -> packed 16B stores.
//         q (scaled by QSCALE), k normal [B,H,S,dk]; V TRANSPOSED [B,H,dk,S].
// MODE 1: attn-out epilogue (out = acc + bo + x residual, fp32, coalesced)
template <int MODE>
__global__ __launch_bounds__(256) void gemm_bt_kernel(
    const unsigned short* __restrict__ A, const unsigned short* __restrict__ Bt,
    int M, int N, int K,
    unsigned short* __restrict__ qb, unsigned short* __restrict__ kb,
    unsigned short* __restrict__ vbT,
    const float* __restrict__ bq, const float* __restrict__ bk,
    const float* __restrict__ bv,
    const float* __restrict__ xres, const float* __restrict__ bo,
    float* __restrict__ out) {
    __shared__ unsigned short smem[17408];  // Al(8192) + Bl(8192) | Ct(128x136)
    unsigned short* Al = smem;
    unsigned short* Bl = smem + 8192;
    unsigned short* Ct = smem;
    int tid = threadIdx.x;
    int m0 = blockIdx.y * 128, n0 = blockIdx.x * 128;
    int w = tid >> 6, l = tid & 63, g = l >> 4, lr = l & 15;
    int wr = (w >> 1) * 64, wc = (w & 1) * 64;
    int srow = tid >> 3, scol = (tid & 7) * 8;
    unsigned short* AlW = Al + w * 512;  // wave-uniform LDS base
    unsigned short* BlW = Bl + w * 512;
    f32x4 acc[4][4];
    for (int i = 0; i < 4; ++i)
        for (int j = 0; j < 4; ++j)
            for (int e = 0; e < 4; ++e) acc[i][j][e] = 0.0f;

    for (int k0 = 0; k0 < K; k0 += 64) {
        const unsigned short* Ap = A + (size_t)(m0 + srow) * K + k0 + scol;
        const unsigned short* Bp = Bt + (size_t)(n0 + srow) * K + k0 + scol;
        for (int i = 0; i < 4; ++i) gload16(Ap + (size_t)i * 32 * K, AlW + i * 2048);
        for (int i = 0; i < 4; ++i) gload16(Bp + (size_t)i * 32 * K, BlW + i * 2048);
        __syncthreads();
        for (int kk = 0; kk < 64; kk += 32) {
            short8 af[4], bf[4];
            for (int mi = 0; mi < 4; ++mi)
                af[mi] = *reinterpret_cast<const short8*>(&Al[(wr + mi * 16 + lr) * 64 + kk + g * 8]);
            for (int ni = 0; ni < 4; ++ni)
                bf[ni] = *reinterpret_cast<const short8*>(&Bl[(wc + ni * 16 + lr) * 64 + kk + g * 8]);
            for (int mi = 0; mi < 4; ++mi)
                for (int ni = 0; ni < 4; ++ni)
                    acc[mi][ni] = __builtin_amdgcn_mfma_f32_16x16x32_bf16(
                        af[mi], bf[ni], acc[mi][ni], 0, 0, 0);
        }
        __syncthreads();
    }

    if (MODE == 0) {
        // Stage tile into LDS (bias added, bf16), V-blocks transposed.
        bool isv = (n0 >= 2048);
        bool isq = (n0 < 1024);
        const float* bias = isq ? bq : (n0 < 2048) ? bk : bv;
        int nb = n0 & 1023;
        for (int mi = 0; mi < 4; ++mi)
            for (int ni = 0; ni < 4; ++ni) {
                int cl = wc + ni * 16 + lr;
                for (int r = 0; r < 4; ++r) {
                    int ml = wr + mi * 16 + g * 4 + r;
                    float vv = acc[mi][ni][r] + bias[nb + cl];
                    if (isq) vv *= QSCALE;  // fold softmax scale + log2e into q
                    unsigned short bfv = f2bf(vv);
                    if (isv) Ct[cl * 136 + ml] = bfv;
                    else     Ct[ml * 136 + cl] = bfv;
                }
            }
        __syncthreads();
        // Cooperative packed write-out: 16 chunks x 128 rows of short8.
        int chunk = tid & 15, rowb = tid >> 4;
        int bb = m0 >> 11, s0 = m0 & 2047;
        for (int it = 0; it < 8; ++it) {
            int rr = it * 16 + rowb;
            short8 vd = *reinterpret_cast<const short8*>(&Ct[rr * 136 + chunk * 8]);
            if (isv) {
                int nn = nb + rr, hh = nn >> 6, kk2 = nn & 63;
                *reinterpret_cast<short8*>(
                    &vbT[(((size_t)bb * NH + hh) * DK + kk2) * S_LEN + s0 + chunk * 8]) = vd;
            } else {
                int nn = nb + chunk * 8, hh = nn >> 6, kk2 = nn & 63;
                unsigned short* dst = isq ? qb : kb;
                *reinterpret_cast<short8*>(
                    &dst[(((size_t)bb * NH + hh) * S_LEN + s0 + rr) * DK + kk2]) = vd;
            }
        }
    } else {
        for (int mi = 0; mi < 4; ++mi)
            for (int ni = 0; ni < 4; ++ni) {
                int col = n0 + wc + ni * 16 + lr;
                for (int r = 0; r < 4; ++r) {
                    int m = m0 + wr + mi * 16 + g * 4 + r;
                    out[(size_t)m * DMODEL + col] =
                        acc[mi][ni][r] + bo[col] + xres[(size_t)m * DMODEL + col];
                }
            }
    }
}

// ---------------- flash attention, causal ----------------
// Block = 512 threads = 8 waves: waves 0-3 own Q-tile `pair`, waves 4-7 own
// Q-tile `31-pair` (load balance), SHARING each staged KV tile (one stage per
// tile per block). Blocks XCD-grouped so one XCD's blocks cover 8 (b,h) heads
// (KV working set = 4MB = L2). 2 barriers per tile (P is wave-private in LDS).
__global__ __launch_bounds__(512) void attn_kernel(const unsigned short* __restrict__ qb,
                                                   const unsigned short* __restrict__ kb,
                                                   const unsigned short* __restrict__ vbT,
                                                   unsigned short* __restrict__ ctx) {
    __shared__ unsigned short Kl[64][72];
    __shared__ unsigned short Vt[64][72];
    __shared__ unsigned short Pl[128][72];
    int j = blockIdx.x;
    int L = ((j & 7) << 7) | (j >> 3);  // XCD-contiguous remap (1024 blocks, 8 XCDs)
    int pair = L & 15, h = (L >> 4) & 15, b = L >> 8;
    size_t base = ((size_t)b * NH + h) * S_LEN * DK;
    int tid = threadIdx.x, w = tid >> 6, l = tid & 63, g = l >> 4, lr = l & 15;
    int si = w >> 2, ws = w & 3;          // segment (0/1), wave-in-segment
    int myqt = si ? 31 - pair : pair;     // this wave's Q-tile
    int q0 = myqt * 64;
    int nt = 32 - pair;                   // KV tiles staged by the block
    int r8 = tid >> 3, c8 = (tid & 7) * 8;
    int prow = si * 64 + ws * 16;         // this wave's P rows in Pl

    uint4 kreg, vreg;
    kreg = *reinterpret_cast<const uint4*>(&kb[base + (size_t)r8 * DK + c8]);
    vreg = *reinterpret_cast<const uint4*>(&vbT[base + (size_t)r8 * S_LEN + c8]);

    short8 qf[2];
    for (int ks = 0; ks < 2; ++ks)
        qf[ks] = *reinterpret_cast<const short8*>(
            &qb[base + (size_t)(q0 + ws * 16 + lr) * DK + ks * 32 + g * 8]);

    f32x4 ctxa[4];
    for (int f = 0; f < 4; ++f)
        for (int e = 0; e < 4; ++e) ctxa[f][e] = 0.0f;
    float m_r[4], lsum[4];
    for (int r = 0; r < 4; ++r) { m_r[r] = -3e38f; lsum[r] = 0.f; }

    for (int t = 0; t < nt; ++t) {
        int kv0 = t * 64;
        __syncthreads();  // previous tile's Kl/Vt reads complete
        *reinterpret_cast<uint4*>(&Kl[r8][c8]) = kreg;
        *reinterpret_cast<uint4*>(&Vt[r8][c8]) = vreg;
        __syncthreads();
        {  // prefetch next tile under compute
            int nkv = (t + 1 < nt) ? kv0 + 64 : 0;
            kreg = *reinterpret_cast<const uint4*>(&kb[base + (size_t)(nkv + r8) * DK + c8]);
            vreg = *reinterpret_cast<const uint4*>(&vbT[base + (size_t)r8 * S_LEN + nkv + c8]);
        }
        if (t > myqt) continue;  // wave-uniform: this segment is done

        f32x4 sc[4];
        for (int f = 0; f < 4; ++f)
            for (int e = 0; e < 4; ++e) sc[f][e] = 0.0f;
        __builtin_amdgcn_s_setprio(1);
        for (int ks = 0; ks < 2; ++ks)
            for (int f = 0; f < 4; ++f) {
                short8 kf = *reinterpret_cast<const short8*>(&Kl[f * 16 + lr][ks * 32 + g * 8]);
                sc[f] = __builtin_amdgcn_mfma_f32_16x16x32_bf16(qf[ks], kf, sc[f], 0, 0, 0);
            }
        __builtin_amdgcn_s_setprio(0);
        if (t == myqt) {  // diagonal tile: causal mask
            for (int f = 0; f < 4; ++f)
                for (int r = 0; r < 4; ++r) {
                    int colg = kv0 + f * 16 + lr;
                    int rowg = q0 + ws * 16 + g * 4 + r;
                    if (colg > rowg) sc[f][r] = -3e38f;
                }
        }
        float tm[4];
        for (int r = 0; r < 4; ++r)
            tm[r] = fmaxf(fmaxf(sc[0][r], sc[1][r]), fmaxf(sc[2][r], sc[3][r]));
        bool ok = tm[0] <= m_r[0] + 8.f && tm[1] <= m_r[1] + 8.f &&
                  tm[2] <= m_r[2] + 8.f && tm[3] <= m_r[3] + 8.f;
        if (!__all((int)ok)) {  // rescale path (rare after warm-up)
            for (int mk = 1; mk < 16; mk <<= 1)
                for (int r = 0; r < 4; ++r) tm[r] = fmaxf(tm[r], __shfl_xor(tm[r], mk));
            for (int r = 0; r < 4; ++r) {
                float mn = fmaxf(m_r[r], tm[r]);
                float al = fast_exp2(m_r[r] - mn);
                m_r[r] = mn;
                lsum[r] *= al;
                for (int f = 0; f < 4; ++f) ctxa[f][r] *= al;
            }
        }
        for (int f = 0; f < 4; ++f)
            for (int r = 0; r < 4; ++r) {
                float p = fast_exp2(sc[f][r] - m_r[r]);
                lsum[r] += p;
                Pl[prow + g * 4 + r][f * 16 + lr] = f2bf(p);
            }
        // P rows are wave-private: no barrier needed (lgkmcnt ordering suffices)
        __builtin_amdgcn_s_setprio(1);
        for (int ks = 0; ks < 2; ++ks) {
            short8 pa = *reinterpret_cast<const short8*>(&Pl[prow + lr][ks * 32 + g * 8]);
            for (int f = 0; f < 4; ++f) {
                short8 vf = *reinterpret_cast<const short8*>(&Vt[f * 16 + lr][ks * 32 + g * 8]);
                ctxa[f] = __builtin_amdgcn_mfma_f32_16x16x32_bf16(pa, vf, ctxa[f], 0, 0, 0);
            }
        }
        __builtin_amdgcn_s_setprio(0);
    }
    // deferred l reduction (once per wave)
    for (int mk = 1; mk < 16; mk <<= 1)
        for (int r = 0; r < 4; ++r) lsum[r] += __shfl_xor(lsum[r], mk);
    float inv[4];
    for (int r = 0; r < 4; ++r) inv[r] = 1.0f / lsum[r];
    for (int f = 0; f < 4; ++f)
        for (int r = 0; r < 4; ++r) {
            int s = q0 + ws * 16 + g * 4 + r;
            int d = f * 16 + lr;
            ctx[(((size_t)b * S_LEN + s) * NH + h) * DK + d] = f2bf(ctxa[f][r] * inv[r]);
        }
}

// ---------------- LayerNorm in-place on d_out ----------------
__global__ __launch_bounds__(256) void ln_kernel(float* __restrict__ y,
                                                 const float* __restrict__ gamma,
                                                 const float* __restrict__ beta) {
    int row = blockIdx.x, tid = threadIdx.x;
    float4 v = reinterpret_cast<const float4*>(y + (size_t)row * DMODEL)[tid];
    float s = v.x + v.y + v.z + v.w;
    float q = v.x * v.x + v.y * v.y + v.z * v.z + v.w * v.w;
    for (int off = 32; off >= 1; off >>= 1) {
        s += __shfl_down(s, off);
        q += __shfl_down(q, off);
    }
    __shared__ float ss[4], sq[4];
    int w = tid >> 6, l = tid & 63;
    if (l == 0) { ss[w] = s; sq[w] = q; }
    __syncthreads();
    s = ss[0] + ss[1] + ss[2] + ss[3];
    q = sq[0] + sq[1] + sq[2] + sq[3];
    float mu = s * (1.0f / 1024.0f);
    float var = q * (1.0f / 1024.0f) - mu * mu;
    float inv = rsqrtf(var + 1e-6f);
    float4 g4 = reinterpret_cast<const float4*>(gamma)[tid];
    float4 b4 = reinterpret_cast<const float4*>(beta)[tid];
    float4 o;
    o.x = (v.x - mu) * inv * g4.x + b4.x;
    o.y = (v.y - mu) * inv * g4.y + b4.y;
    o.z = (v.z - mu) * inv * g4.z + b4.z;
    o.w = (v.w - mu) * inv * g4.w + b4.w;
    reinterpret_cast<float4*>(y + (size_t)row * DMODEL)[tid] = o;
}

extern "C" void kernel_launch(void* const* d_in, const int* in_sizes, int n_in,
                              void* d_out, int out_size, void* d_ws, size_t ws_size,
                              hipStream_t stream) {
    const float* x     = (const float*)d_in[0];
    const float* Wq    = (const float*)d_in[1];
    const float* bq    = (const float*)d_in[2];
    const float* Wk    = (const float*)d_in[3];
    const float* bk    = (const float*)d_in[4];
    const float* Wv    = (const float*)d_in[5];
    const float* bv    = (const float*)d_in[6];
    const float* Wo    = (const float*)d_in[7];
    const float* bo    = (const float*)d_in[8];
    const float* gamma = (const float*)d_in[9];
    const float* beta  = (const float*)d_in[10];
    float* out = (float*)d_out;
    char* ws = (char*)d_ws;
    unsigned short* xbf   = (unsigned short*)(ws);              // 16 MB (reused as ctx)
    unsigned short* wqkvT = (unsigned short*)(ws + 16777216);   // 6 MB  [3072][1024]
    unsigned short* woT   = (unsigned short*)(ws + 23068672);   // 2 MB  [1024][1024]
    unsigned short* qbuf  = (unsigned short*)(ws + 25165824);   // 16 MB [B,H,S,dk] (pre-scaled)
    unsigned short* kbuf  = (unsigned short*)(ws + 41943040);   // 16 MB [B,H,S,dk]
    unsigned short* vbufT = (unsigned short*)(ws + 58720256);   // 16 MB [B,H,dk,S]
    unsigned short* ctx   = xbf;  // xbf dead after QKV GEMM

    cast_x_kernel<<<8192, 256, 0, stream>>>(x, xbf, 2097152);
    dim3 tg(16, 16, 4);
    transpose_cast_kernel<<<tg, 256, 0, stream>>>(Wq, Wk, Wv, Wo, wqkvT,
                                                  wqkvT + 1048576, wqkvT + 2097152, woT);

    dim3 g1(24, 64);
    gemm_bt_kernel<0><<<g1, 256, 0, stream>>>(xbf, wqkvT, 8192, 3072, 1024,
                                              qbuf, kbuf, vbufT, bq, bk, bv,
                                              nullptr, nullptr, nullptr);
    attn_kernel<<<1024, 512, 0, stream>>>(qbuf, kbuf, vbufT, ctx);

    dim3 g2(8, 64);
    gemm_bt_kernel<1><<<g2, 256, 0, stream>>>(ctx, woT, 8192, 1024, 1024,
                                              nullptr, nullptr, nullptr,
                                              nullptr, nullptr, nullptr,
                                              x, bo, out);
    ln_kernel<<<8192, 256, 0, stream>>>(out, gamma, beta);
}

// Round 10
// 317.260 us; speedup vs baseline: 2.2179x; 1.0154x over previous
//
#include <hip/hip_runtime.h>

// Fused causal self-attention block: B=4, S=2048, D=1024, H=16, dk=64.
// cast/transpose -> QKV GEMM (global_load_lds; LDS-bounce epilogue, q pre-scaled
// by 0.125*log2e, V stored transposed; XCD-swizzled grid) -> flash attention
// (512-thr block, shared KV staging, swapped QK^T -> in-register softmax via
// cvt_pk + permuted-contraction PV, no P LDS) -> out GEMM + residual -> LN.

typedef __attribute__((ext_vector_type(8))) short short8;
typedef __attribute__((ext_vector_type(4))) float f32x4;

#define S_LEN 2048
#define NH 16
#define DK 64
#define DMODEL 1024
#define QSCALE 0.18033688011112042f  // 0.125 * log2(e)

__device__ inline float fast_exp2(float x) { return __builtin_amdgcn_exp2f(x); }

__device__ inline unsigned short f2bf(float f) {
    unsigned int u = __builtin_bit_cast(unsigned int, f);
    unsigned int r = (u + 0x7fffu + ((u >> 16) & 1u)) >> 16;  // RNE
    return (unsigned short)r;
}

__device__ inline unsigned int cvt_pk_bf16(float lo, float hi) {
    unsigned int r;
    asm("v_cvt_pk_bf16_f32 %0, %1, %2" : "=v"(r) : "v"(lo), "v"(hi));
    return r;
}

__device__ inline void gload16(const unsigned short* g, unsigned short* lds) {
    __builtin_amdgcn_global_load_lds(
        (const __attribute__((address_space(1))) void*)g,
        (__attribute__((address_space(3))) void*)lds, 16, 0, 0);
}

// ---------------- cast x (fp32 -> bf16) ----------------
__global__ __launch_bounds__(256) void cast_x_kernel(const float* __restrict__ x,
                                                     unsigned short* __restrict__ xb,
                                                     int n4) {
    int i = blockIdx.x * 256 + threadIdx.x;
    if (i >= n4) return;
    float4 v = reinterpret_cast<const float4*>(x)[i];
    ushort4 o;
    o.x = f2bf(v.x); o.y = f2bf(v.y); o.z = f2bf(v.z); o.w = f2bf(v.w);
    reinterpret_cast<ushort4*>(xb)[i] = o;
}

// ---------------- tiled 1024x1024 transpose fp32 -> bf16 ----------------
__global__ __launch_bounds__(256) void transpose_cast_kernel(
    const float* __restrict__ s0, const float* __restrict__ s1,
    const float* __restrict__ s2, const float* __restrict__ s3,
    unsigned short* __restrict__ d0, unsigned short* __restrict__ d1,
    unsigned short* __restrict__ d2, unsigned short* __restrict__ d3) {
    int z = blockIdx.z;
    const float* in = z == 0 ? s0 : z == 1 ? s1 : z == 2 ? s2 : s3;
    unsigned short* out = z == 0 ? d0 : z == 1 ? d1 : z == 2 ? d2 : d3;
    __shared__ float t[64][65];
    int i0 = blockIdx.x * 64, j0 = blockIdx.y * 64;
    int tid = threadIdx.x, r = tid >> 4, c4 = (tid & 15) * 4;
    for (int rr = 0; rr < 4; ++rr) {
        float4 v = *reinterpret_cast<const float4*>(&in[(size_t)(i0 + rr * 16 + r) * 1024 + j0 + c4]);
        t[rr * 16 + r][c4 + 0] = v.x; t[rr * 16 + r][c4 + 1] = v.y;
        t[rr * 16 + r][c4 + 2] = v.z; t[rr * 16 + r][c4 + 3] = v.w;
    }
    __syncthreads();
    for (int rr = 0; rr < 4; ++rr) {
        int orow = rr * 16 + r;
        ushort4 o;
        o.x = f2bf(t[c4 + 0][orow]); o.y = f2bf(t[c4 + 1][orow]);
        o.z = f2bf(t[c4 + 2][orow]); o.w = f2bf(t[c4 + 3][orow]);
        *reinterpret_cast<ushort4*>(&out[(size_t)(j0 + orow) * 1024 + i0 + c4]) = o;
    }
}

// ---------------- GEMM  C[M,N] = A[M,K] * Bt[N,K]^T ----------------
// 128x128 tile, BK=64, global_load_lds staging; XCD-chunked block remap.
// MODE 0: QKV epilogue via LDS bounce -> packed 16B stores.
// MODE 1: attn-out epilogue (out = acc + bo + x residual, fp32, coalesced)
template <int MODE>
__global__ __launch_bounds__(256) void gemm_bt_kernel(
    const unsigned short* __restrict__ A, const unsigned short* __restrict__ Bt,
    int M, int N, int K,
    unsigned short* __restrict__ qb, unsigned short* __restrict__ kb,
    unsigned short* __restrict__ vbT,
    const float* __restrict__ bq, const float* __restrict__ bk,
    const float* __restrict__ bv,
    const float* __restrict__ xres, const float* __restrict__ bo,
    float* __restrict__ out) {
    __shared__ unsigned short smem[17408];  // Al(8192) + Bl(8192) | Ct(128x136)
    unsigned short* Al = smem;
    unsigned short* Bl = smem + 8192;
    unsigned short* Ct = smem;
    int tid = threadIdx.x;
    // XCD-chunked bijective remap (grid sizes divisible by 8)
    int id = blockIdx.y * gridDim.x + blockIdx.x;
    int cpx = (gridDim.x * gridDim.y) >> 3;
    int L = (id & 7) * cpx + (id >> 3);
    int m0 = (L / gridDim.x) * 128, n0 = (L % gridDim.x) * 128;
    int w = tid >> 6, l = tid & 63, g = l >> 4, lr = l & 15;
    int wr = (w >> 1) * 64, wc = (w & 1) * 64;
    int srow = tid >> 3, scol = (tid & 7) * 8;
    unsigned short* AlW = Al + w * 512;  // wave-uniform LDS base
    unsigned short* BlW = Bl + w * 512;
    f32x4 acc[4][4];
    for (int i = 0; i < 4; ++i)
        for (int j = 0; j < 4; ++j)
            for (int e = 0; e < 4; ++e) acc[i][j][e] = 0.0f;

    for (int k0 = 0; k0 < K; k0 += 64) {
        const unsigned short* Ap = A + (size_t)(m0 + srow) * K + k0 + scol;
        const unsigned short* Bp = Bt + (size_t)(n0 + srow) * K + k0 + scol;
        for (int i = 0; i < 4; ++i) gload16(Ap + (size_t)i * 32 * K, AlW + i * 2048);
        for (int i = 0; i < 4; ++i) gload16(Bp + (size_t)i * 32 * K, BlW + i * 2048);
        __syncthreads();
        for (int kk = 0; kk < 64; kk += 32) {
            short8 af[4], bf[4];
            for (int mi = 0; mi < 4; ++mi)
                af[mi] = *reinterpret_cast<const short8*>(&Al[(wr + mi * 16 + lr) * 64 + kk + g * 8]);
            for (int ni = 0; ni < 4; ++ni)
                bf[ni] = *reinterpret_cast<const short8*>(&Bl[(wc + ni * 16 + lr) * 64 + kk + g * 8]);
            for (int mi = 0; mi < 4; ++mi)
                for (int ni = 0; ni < 4; ++ni)
                    acc[mi][ni] = __builtin_amdgcn_mfma_f32_16x16x32_bf16(
                        af[mi], bf[ni], acc[mi][ni], 0, 0, 0);
        }
        __syncthreads();
    }

    if (MODE == 0) {
        bool isv = (n0 >= 2048);
        bool isq = (n0 < 1024);
        const float* bias = isq ? bq : (n0 < 2048) ? bk : bv;
        int nb = n0 & 1023;
        for (int mi = 0; mi < 4; ++mi)
            for (int ni = 0; ni < 4; ++ni) {
                int cl = wc + ni * 16 + lr;
                for (int r = 0; r < 4; ++r) {
                    int ml = wr + mi * 16 + g * 4 + r;
                    float vv = acc[mi][ni][r] + bias[nb + cl];
                    if (isq) vv *= QSCALE;  // fold softmax scale + log2e into q
                    unsigned short bfv = f2bf(vv);
                    if (isv) Ct[cl * 136 + ml] = bfv;
                    else     Ct[ml * 136 + cl] = bfv;
                }
            }
        __syncthreads();
        int chunk = tid & 15, rowb = tid >> 4;
        int bb = m0 >> 11, s0 = m0 & 2047;
        for (int it = 0; it < 8; ++it) {
            int rr = it * 16 + rowb;
            short8 vd = *reinterpret_cast<const short8*>(&Ct[rr * 136 + chunk * 8]);
            if (isv) {
                int nn = nb + rr, hh = nn >> 6, kk2 = nn & 63;
                *reinterpret_cast<short8*>(
                    &vbT[(((size_t)bb * NH + hh) * DK + kk2) * S_LEN + s0 + chunk * 8]) = vd;
            } else {
                int nn = nb + chunk * 8, hh = nn >> 6, kk2 = nn & 63;
                unsigned short* dst = isq ? qb : kb;
                *reinterpret_cast<short8*>(
                    &dst[(((size_t)bb * NH + hh) * S_LEN + s0 + rr) * DK + kk2]) = vd;
            }
        }
    } else {
        for (int mi = 0; mi < 4; ++mi)
            for (int ni = 0; ni < 4; ++ni) {
                int col = n0 + wc + ni * 16 + lr;
                for (int r = 0; r < 4; ++r) {
                    int m = m0 + wr + mi * 16 + g * 4 + r;
                    out[(size_t)m * DMODEL + col] =
                        acc[mi][ni][r] + bo[col] + xres[(size_t)m * DMODEL + col];
                }
            }
    }
}

// ---------------- flash attention, causal ----------------
// 512-thr block: waves 0-3 own Q-tile `pair`, waves 4-7 own `31-pair`, sharing
// each staged KV tile. Swapped QK^T: sc=mfma(K,Q) -> lane holds P[kv][q=lr]
// (q lane-local). P packed in-register (cvt_pk) into a permuted-contraction
// A-fragment; V^T read with matching permuted columns (2x ds_read_b64). No P LDS.
__global__ __launch_bounds__(512) void attn_kernel(const unsigned short* __restrict__ qb,
                                                   const unsigned short* __restrict__ kb,
                                                   const unsigned short* __restrict__ vbT,
                                                   unsigned short* __restrict__ ctx) {
    __shared__ unsigned short Kl[64][72];
    __shared__ unsigned short Vt[64][72];
    int j = blockIdx.x;
    int L = ((j & 7) << 7) | (j >> 3);  // XCD-contiguous remap (1024 blocks, 8 XCDs)
    int pair = L & 15, h = (L >> 4) & 15, b = L >> 8;
    size_t base = ((size_t)b * NH + h) * S_LEN * DK;
    int tid = threadIdx.x, w = tid >> 6, l = tid & 63, g = l >> 4, lr = l & 15;
    int si = w >> 2, ws = w & 3;          // segment (0/1), wave-in-segment
    int myqt = si ? 31 - pair : pair;     // this wave's Q-tile
    int q0 = myqt * 64;
    int nt = 32 - pair;                   // KV tiles staged by the block
    int r8 = tid >> 3, c8 = (tid & 7) * 8;

    uint4 kreg, vreg;
    kreg = *reinterpret_cast<const uint4*>(&kb[base + (size_t)r8 * DK + c8]);
    vreg = *reinterpret_cast<const uint4*>(&vbT[base + (size_t)r8 * S_LEN + c8]);

    short8 qf[2];
    for (int ks = 0; ks < 2; ++ks)
        qf[ks] = *reinterpret_cast<const short8*>(
            &qb[base + (size_t)(q0 + ws * 16 + lr) * DK + ks * 32 + g * 8]);

    f32x4 ctxa[4];
    for (int f = 0; f < 4; ++f)
        for (int e = 0; e < 4; ++e) ctxa[f][e] = 0.0f;
    float m_s = -3e38f, lsum = 0.f;  // for q-row = lr (lane-local)

    for (int t = 0; t < nt; ++t) {
        int kv0 = t * 64;
        __syncthreads();  // previous tile's Kl/Vt reads complete
        *reinterpret_cast<uint4*>(&Kl[r8][c8]) = kreg;
        *reinterpret_cast<uint4*>(&Vt[r8][c8]) = vreg;
        __syncthreads();
        {  // prefetch next tile under compute
            int nkv = (t + 1 < nt) ? kv0 + 64 : 0;
            kreg = *reinterpret_cast<const uint4*>(&kb[base + (size_t)(nkv + r8) * DK + c8]);
            vreg = *reinterpret_cast<const uint4*>(&vbT[base + (size_t)r8 * S_LEN + nkv + c8]);
        }
        if (t > myqt) continue;  // wave-uniform: this segment done (parked on barriers)

        // swapped QK^T: sc[fa] reg r = P[kv = kv0+fa*16+g*4+r][q = q0+ws*16+lr]
        f32x4 sc[4];
        for (int fa = 0; fa < 4; ++fa)
            for (int e = 0; e < 4; ++e) sc[fa][e] = 0.0f;
        __builtin_amdgcn_s_setprio(1);
        for (int ks = 0; ks < 2; ++ks)
            for (int fa = 0; fa < 4; ++fa) {
                short8 kf = *reinterpret_cast<const short8*>(&Kl[fa * 16 + lr][ks * 32 + g * 8]);
                sc[fa] = __builtin_amdgcn_mfma_f32_16x16x32_bf16(kf, qf[ks], sc[fa], 0, 0, 0);
            }
        __builtin_amdgcn_s_setprio(0);
        if (t == myqt) {  // diagonal tile: causal mask
            int qg = q0 + ws * 16 + lr;
            for (int fa = 0; fa < 4; ++fa)
                for (int r = 0; r < 4; ++r)
                    if (kv0 + fa * 16 + g * 4 + r > qg) sc[fa][r] = -3e38f;
        }
        // row-max for q=lr: 16 local values + 2 cross-g shuffles
        float tm = sc[0][0];
        for (int fa = 0; fa < 4; ++fa)
            for (int r = 0; r < 4; ++r) tm = fmaxf(tm, sc[fa][r]);
        tm = fmaxf(tm, __shfl_xor(tm, 16));
        tm = fmaxf(tm, __shfl_xor(tm, 32));
        bool ok = tm <= m_s + 8.f;
        if (!__all((int)ok)) {  // rescale (rare): alpha lives at q=lr, ctx rows q=g*4+r
            float mn = fmaxf(m_s, tm);
            float al = fast_exp2(m_s - mn);
            m_s = mn;
            lsum *= al;
            float ar[4];
            for (int r = 0; r < 4; ++r) ar[r] = __shfl(al, g * 4 + r);
            for (int f = 0; f < 4; ++f)
                for (int r = 0; r < 4; ++r) ctxa[f][r] *= ar[r];
        }
        // P = exp2(sc - m), packed lane-locally into permuted A-fragments
        float p[4][4];
        float ls = 0.f;
        for (int fa = 0; fa < 4; ++fa)
            for (int r = 0; r < 4; ++r) {
                p[fa][r] = fast_exp2(sc[fa][r] - m_s);
                ls += p[fa][r];
            }
        lsum += ls;
        unsigned int pk[4][2];
        for (int fa = 0; fa < 4; ++fa) {
            pk[fa][0] = cvt_pk_bf16(p[fa][0], p[fa][1]);
            pk[fa][1] = cvt_pk_bf16(p[fa][2], p[fa][3]);
        }
        uint4 pa0u = {pk[0][0], pk[0][1], pk[1][0], pk[1][1]};
        uint4 pa1u = {pk[2][0], pk[2][1], pk[3][0], pk[3][1]};
        short8 pa0 = __builtin_bit_cast(short8, pa0u);
        short8 pa1 = __builtin_bit_cast(short8, pa1u);
        // PV with permuted contraction: A slot j <-> kv = 32ks+16(j>>2)+4g+(j&3);
        // B read from Vt at cols {32ks+4g+0..3, 32ks+16+4g+0..3}.
        __builtin_amdgcn_s_setprio(1);
        for (int ks = 0; ks < 2; ++ks) {
            short8 pa = ks ? pa1 : pa0;
            for (int f = 0; f < 4; ++f) {
                const unsigned short* vrow = &Vt[f * 16 + lr][0];
                uint2 lo = *reinterpret_cast<const uint2*>(&vrow[ks * 32 + 4 * g]);
                uint2 hi = *reinterpret_cast<const uint2*>(&vrow[ks * 32 + 16 + 4 * g]);
                uint4 vfu = {lo.x, lo.y, hi.x, hi.y};
                short8 vf = __builtin_bit_cast(short8, vfu);
                ctxa[f] = __builtin_amdgcn_mfma_f32_16x16x32_bf16(pa, vf, ctxa[f], 0, 0, 0);
            }
        }
        __builtin_amdgcn_s_setprio(0);
    }
    // final: lsum lives at q=lr; ctx rows need q=g*4+r
    lsum += __shfl_xor(lsum, 16);
    lsum += __shfl_xor(lsum, 32);
    float rl = 1.0f / lsum;
    float inv_l[4];
    for (int r = 0; r < 4; ++r) inv_l[r] = __shfl(rl, g * 4 + r);
    for (int f = 0; f < 4; ++f)
        for (int r = 0; r < 4; ++r) {
            int s = q0 + ws * 16 + g * 4 + r;
            int d = f * 16 + lr;
            ctx[(((size_t)b * S_LEN + s) * NH + h) * DK + d] = f2bf(ctxa[f][r] * inv_l[r]);
        }
}

// ---------------- LayerNorm in-place on d_out ----------------
__global__ __launch_bounds__(256) void ln_kernel(float* __restrict__ y,
                                                 const float* __restrict__ gamma,
                                                 const float* __restrict__ beta) {
    int row = blockIdx.x, tid = threadIdx.x;
    float4 v = reinterpret_cast<const float4*>(y + (size_t)row * DMODEL)[tid];
    float s = v.x + v.y + v.z + v.w;
    float q = v.x * v.x + v.y * v.y + v.z * v.z + v.w * v.w;
    for (int off = 32; off >= 1; off >>= 1) {
        s += __shfl_down(s, off);
        q += __shfl_down(q, off);
    }
    __shared__ float ss[4], sq[4];
    int w = tid >> 6, l = tid & 63;
    if (l == 0) { ss[w] = s; sq[w] = q; }
    __syncthreads();
    s = ss[0] + ss[1] + ss[2] + ss[3];
    q = sq[0] + sq[1] + sq[2] + sq[3];
    float mu = s * (1.0f / 1024.0f);
    float var = q * (1.0f / 1024.0f) - mu * mu;
    float inv = rsqrtf(var + 1e-6f);
    float4 g4 = reinterpret_cast<const float4*>(gamma)[tid];
    float4 b4 = reinterpret_cast<const float4*>(beta)[tid];
    float4 o;
    o.x = (v.x - mu) * inv * g4.x + b4.x;
    o.y = (v.y - mu) * inv * g4.y + b4.y;
    o.z = (v.z - mu) * inv * g4.z + b4.z;
    o.w = (v.w - mu) * inv * g4.w + b4.w;
    reinterpret_cast<float4*>(y + (size_t)row * DMODEL)[tid] = o;
}

extern "C" void kernel_launch(void* const* d_in, const int* in_sizes, int n_in,
                              void* d_out, int out_size, void* d_ws, size_t ws_size,
                              hipStream_t stream) {
    const float* x     = (const float*)d_in[0];
    const float* Wq    = (const float*)d_in[1];
    const float* bq    = (const float*)d_in[2];
    const float* Wk    = (const float*)d_in[3];
    const float* bk    = (const float*)d_in[4];
    const float* Wv    = (const float*)d_in[5];
    const float* bv    = (const float*)d_in[6];
    const float* Wo    = (const float*)d_in[7];
    const float* bo    = (const float*)d_in[8];
    const float* gamma = (const float*)d_in[9];
    const float* beta  = (const float*)d_in[10];
    float* out = (float*)d_out;
    char* ws = (char*)d_ws;
    unsigned short* xbf   = (unsigned short*)(ws);              // 16 MB (reused as ctx)
    unsigned short* wqkvT = (unsigned short*)(ws + 16777216);   // 6 MB  [3072][1024]
    unsigned short* woT   = (unsigned short*)(ws + 23068672);   // 2 MB  [1024][1024]
    unsigned short* qbuf  = (unsigned short*)(ws + 25165824);   // 16 MB [B,H,S,dk] (pre-scaled)
    unsigned short* kbuf  = (unsigned short*)(ws + 41943040);   // 16 MB [B,H,S,dk]
    unsigned short* vbufT = (unsigned short*)(ws + 58720256);   // 16 MB [B,H,dk,S]
    unsigned short* ctx   = xbf;  // xbf dead after QKV GEMM

    cast_x_kernel<<<8192, 256, 0, stream>>>(x, xbf, 2097152);
    dim3 tg(16, 16, 4);
    transpose_cast_kernel<<<tg, 256, 0, stream>>>(Wq, Wk, Wv, Wo, wqkvT,
                                                  wqkvT + 1048576, wqkvT + 2097152, woT);

    dim3 g1(24, 64);
    gemm_bt_kernel<0><<<g1, 256, 0, stream>>>(xbf, wqkvT, 8192, 3072, 1024,
                                              qbuf, kbuf, vbufT, bq, bk, bv,
                                              nullptr, nullptr, nullptr);
    attn_kernel<<<1024, 512, 0, stream>>>(qbuf, kbuf, vbufT, ctx);

    dim3 g2(8, 64);
    gemm_bt_kernel<1><<<g2, 256, 0, stream>>>(ctx, woT, 8192, 1024, 1024,
                                              nullptr, nullptr, nullptr,
                                              nullptr, nullptr, nullptr,
                                              x, bo, out);
    ln_kernel<<<8192, 256, 0, stream>>>(out, gamma, beta);
}